// Round 4
// baseline (1514.836 us; speedup 1.0000x reference)
//
#include <hip/hip_runtime.h>

#define N_NODES 32768
#define N_EDGES 1048576
#define PREP_L  467968   // prepped bf16 weights per layer

typedef short bfrag8 __attribute__((ext_vector_type(8)));
typedef float f32x4  __attribute__((ext_vector_type(4)));

#define MFMA(a,b,c) __builtin_amdgcn_mfma_f32_16x16x32_bf16(a,b,c,0,0,0)

__device__ __forceinline__ short f2bf(float f){
    unsigned u = __float_as_uint(f);
    u += 0x7fffu + ((u >> 16) & 1u);
    return (short)(u >> 16);
}
__device__ __forceinline__ float sigm(float x){ return 1.0f/(1.0f + __expf(-x)); }
__device__ __forceinline__ float siluf(float x){ return x * sigm(x); }

// ---------------------------------------------------------------- weight prep
__global__ void k_prep(const float* Wss, const float* Wvv0, const float* Wsv,
                       const float* Wvs, const float* Wuss, const float* Wuvv,
                       const float* Wusv, const float* Wuvs, const float* Wout,
                       short* wp)
{
    int idx = blockIdx.x*256 + threadIdx.x;
    const int total = 2*PREP_L + 16384;
    if (idx >= total) return;
    const float s_ss  = 0.0883883476483f;  // 1/(8*sqrt2)
    const float s_vv  = 0.0721687836487f;  // (1/sqrt3)/8
    const float s_sv  = 0.0883883476483f;
    const float s_vs  = 0.125f;
    const float s_uss = 0.0110485434560f;  // 1/(64*sqrt2)
    const float s_uvv = 0.0127577593310f;  // 1/(32*sqrt6)
    const float s_uvw = 0.015625f;         // 1/64
    float v;
    if (idx >= 2*PREP_L){
        int r = idx - 2*PREP_L; int o = r >> 6, i = r & 63;
        v = Wout[i*256 + o] * 0.125f;
    } else {
        int l = idx / PREP_L; int off = idx - l*PREP_L;
        if (off < 6144){ int o = off/96, k = off - o*96;
            v = (k < 64) ? Wss[l*4096 + k*64 + o]*s_ss
                         : Wvv0[l*2048 + (k-64)*64 + o]*s_vv;
        } else if (off < 8192){ int tt = off - 6144; int m = tt>>6, i = tt&63;
            v = Wsv[l*2048 + i*32 + m]*s_sv;
        } else if (off < 9216){ int tt = off - 8192; int n = tt>>5, m = tt&31;
            v = Wvs[l*1024 + m*32 + n]*s_vs;
        } else if (off < 336896){ int tt = off - 9216; int o = tt/5120, k = tt - o*5120;
            if (k < 4096) v = Wuss[l*262144 + k*64 + o]*s_uss;
            else          v = Wuvv[l*65536 + (k-4096)*64 + o]*s_uvv;
        } else if (off < 402432){ int tt = off - 336896; int nf = tt>>6, i = tt&63;
            int n = nf>>5, o = nf&31;
            v = Wusv[l*65536 + i*1024 + n*32 + o]*s_uvw;
        } else { int tt = off - 402432; int nf = tt>>6, j = tt&63;
            int m = nf>>5, o = nf&31;
            v = Wuvs[l*65536 + m*2048 + j*32 + o]*s_uvw;
        }
    }
    wp[idx] = f2bf(v);
}

// ---------------------------------------------------------------- ns = x@Win/8
__global__ void k_in(const float* __restrict__ x, const float* __restrict__ Win,
                     float* __restrict__ ns)
{
    int wv = threadIdx.x >> 6, o = threadIdx.x & 63;
    int node = blockIdx.x*4 + wv;
    const float* xr = x + (size_t)node*64;
    float acc = 0.f;
    #pragma unroll
    for (int i=0;i<64;i++) acc += xr[i]*Win[i*64+o];
    ns[(size_t)node*64+o] = 0.125f*acc;
}

// ---------------------------------------------------------------- sort: histogram
__global__ void k_hist(const int* __restrict__ eidx, int* __restrict__ cnt)
{
    int e = blockIdx.x*256 + threadIdx.x;
    atomicAdd(&cnt[eidx[e]], 1);
}

// ---------------------------------------------------------------- sort: scan (1 block)
__global__ void k_scan(const int* __restrict__ cnt, int* __restrict__ cursor)
{
    __shared__ int part[256];
    int t = threadIdx.x;
    int base = t*128;
    int s = 0;
    for (int i=0;i<128;i++) s += cnt[base+i];
    part[t] = s; __syncthreads();
    for (int off=1; off<256; off<<=1){
        int v = (t>=off) ? part[t-off] : 0;
        __syncthreads();
        part[t] += v;
        __syncthreads();
    }
    int run = part[t] - s;   // exclusive prefix
    for (int i=0;i<128;i++){ cursor[base+i] = run; run += cnt[base+i]; }
}

// ---------------------------------------------------------------- sort: scatter + pre-gather
__global__ void k_scatter(const int* __restrict__ eidx, const float* __restrict__ eattr,
                          int* __restrict__ cursor, int* __restrict__ col_s,
                          int* __restrict__ row_s, float4* __restrict__ ea_s)
{
    int e = blockIdx.x*256 + threadIdx.x;
    int r = eidx[e];
    int d = atomicAdd(&cursor[r], 1);
    row_s[d] = r;
    col_s[d] = eidx[N_EDGES + e];
    ea_s[d]  = ((const float4*)eattr)[e];
}

// ---------------------------------------------------------------- edge phase (sorted slots)
// es/ev factored out of the bf16 A-tiles: stage RAW hs/hv only, apply es per
// C-row in the fp32 epilogue. LDS ~39 KB -> 4 blocks/CU.
__global__ __launch_bounds__(256, 4) void k_edge(
        const float* __restrict__ ns, const float* __restrict__ nv,
        const int* __restrict__ col_s, const int* __restrict__ row_s,
        const float4* __restrict__ ea_s,
        const short* __restrict__ wp_l,
        const float* __restrict__ gmw, const float* __restrict__ gmb,
        float* __restrict__ a_s, float* __restrict__ a_v)
{
    __shared__ __align__(16) short sA1[4][16*36];    // tvv = hv.ev (K=32)
    __shared__ __align__(16) short sA2[4][16*72];    // raw hs (K=64)
    __shared__ __align__(16) short sAv[4][3*16*36];  // raw hv per x (K=32)
    __shared__ int    sRow[4][16];
    __shared__ float4 sEv4[4][16];                   // ev.xyz, es
    __shared__ float  sAcc[16*160];                  // row-window accumulator

    const int t = threadIdx.x;
    const int w = t >> 6, lane = t & 63;
    const int col = lane & 15, quad = lane >> 4;
    const int blockStart = blockIdx.x*256;
    const int rfirst = row_s[blockStart];

    for (int i=t; i<16*160; i+=256) sAcc[i] = 0.f;

    const short* W1t  = wp_l;
    const short* Wsvt = wp_l + 6144;
    const short* Wvst = wp_l + 8192;

    bfrag8 bss[2][4], bvv[4], bsv[2][2], bvs[2];
    #pragma unroll
    for (int s=0;s<2;s++)
        #pragma unroll
        for (int nt=0;nt<4;nt++)
            bss[s][nt] = *(const bfrag8*)(W1t + (nt*16+col)*96 + s*32 + quad*8);
    #pragma unroll
    for (int nt=0;nt<4;nt++)
        bvv[nt] = *(const bfrag8*)(W1t + (nt*16+col)*96 + 64 + quad*8);
    #pragma unroll
    for (int s=0;s<2;s++)
        #pragma unroll
        for (int nt=0;nt<2;nt++)
            bsv[s][nt] = *(const bfrag8*)(Wsvt + (nt*16+col)*64 + s*32 + quad*8);
    #pragma unroll
    for (int nt=0;nt<2;nt++)
        bvs[nt] = *(const bfrag8*)(Wvst + (nt*16+col)*32 + quad*8);

    float gwv[2][3], gbv[2][3];
    #pragma unroll
    for (int h=0;h<2;h++)
        #pragma unroll
        for (int xx=0;xx<3;xx++){
            int k = (h*16+col)*3+xx;
            gwv[h][xx] = gmw[k]; gbv[h][xx] = gmb[k];
        }

    auto emit = [&](int r, int f, float v){
        int rl = r - rfirst;
        if (rl < 16) atomicAdd(&sAcc[rl*160 + f], v);
        else if (f < 64) atomicAdd(&a_s[(size_t)r*64 + f], v);
        else             atomicAdd(&a_v[(size_t)r*96 + f - 64], v);
    };

    __syncthreads();

    for (int it=0; it<4; it++){
        int tileBase = blockStart + w*64 + it*16;
        { // ---- stage: lane (quad q, edge e) ----
            int e = col, q = quad;
            int sg = tileBase + e;
            int c = col_s[sg];
            float4 ea = ea_s[sg];
            const float* nsr = ns + (size_t)c*64 + q*16;
            float4 h4[4]; float hq[16];
            #pragma unroll
            for (int a=0;a<4;a++) h4[a] = *(const float4*)(nsr + 4*a);
            #pragma unroll
            for (int a=0;a<4;a++){ hq[4*a]=h4[a].x; hq[4*a+1]=h4[a].y; hq[4*a+2]=h4[a].z; hq[4*a+3]=h4[a].w; }
            const float* nvr = nv + (size_t)c*96 + q*24;
            float4 g4[6]; float hv[24];
            #pragma unroll
            for (int a=0;a<6;a++) g4[a] = *(const float4*)(nvr + 4*a);
            #pragma unroll
            for (int a=0;a<6;a++){ hv[4*a]=g4[a].x; hv[4*a+1]=g4[a].y; hv[4*a+2]=g4[a].z; hv[4*a+3]=g4[a].w; }
            #pragma unroll
            for (int hk=0; hk<2; hk++){
                bfrag8 vr;
                #pragma unroll
                for (int j=0;j<8;j++) vr[j] = f2bf(hq[hk*8+j]);
                *(bfrag8*)&sA2[w][e*72 + q*16 + hk*8] = vr;
            }
            bfrag8 vt;
            #pragma unroll
            for (int mi=0;mi<8;mi++)
                vt[mi] = f2bf(hv[mi*3]*ea.x + hv[mi*3+1]*ea.y + hv[mi*3+2]*ea.z);
            *(bfrag8*)&sA1[w][e*36 + q*8] = vt;
            #pragma unroll
            for (int xx=0;xx<3;xx++){
                bfrag8 vv;
                #pragma unroll
                for (int mi=0;mi<8;mi++) vv[mi] = f2bf(hv[mi*3+xx]);
                *(bfrag8*)&sAv[w][xx*576 + e*36 + q*8] = vv;
            }
            if (q==0){
                sRow[w][e] = row_s[sg];
                sEv4[w][e] = ea;
            }
        }
        __syncthreads();
        // ---- MFMA ----
        f32x4 accss[4], accvv[4], accp[2], accq[3][2];
        #pragma unroll
        for (int nt=0;nt<4;nt++){ accss[nt] = (f32x4){0.f,0.f,0.f,0.f};
                                  accvv[nt] = (f32x4){0.f,0.f,0.f,0.f}; }
        #pragma unroll
        for (int nt=0;nt<2;nt++) accp[nt] = (f32x4){0.f,0.f,0.f,0.f};
        #pragma unroll
        for (int xx=0;xx<3;xx++)
            #pragma unroll
            for (int nt=0;nt<2;nt++) accq[xx][nt] = (f32x4){0.f,0.f,0.f,0.f};
        bfrag8 a1, a2[2], av3[3];
        a1 = *(bfrag8*)&sA1[w][col*36 + quad*8];
        #pragma unroll
        for (int s=0;s<2;s++) a2[s] = *(bfrag8*)&sA2[w][col*72 + s*32 + quad*8];
        #pragma unroll
        for (int xx=0;xx<3;xx++) av3[xx] = *(bfrag8*)&sAv[w][xx*576 + col*36 + quad*8];
        #pragma unroll
        for (int s=0;s<2;s++)
            #pragma unroll
            for (int nt=0;nt<4;nt++) accss[nt] = MFMA(a2[s], bss[s][nt], accss[nt]);
        #pragma unroll
        for (int nt=0;nt<4;nt++) accvv[nt] = MFMA(a1, bvv[nt], accvv[nt]);
        #pragma unroll
        for (int s=0;s<2;s++)
            #pragma unroll
            for (int nt=0;nt<2;nt++) accp[nt] = MFMA(a2[s], bsv[s][nt], accp[nt]);
        #pragma unroll
        for (int xx=0;xx<3;xx++)
            #pragma unroll
            for (int nt=0;nt<2;nt++) accq[xx][nt] = MFMA(av3[xx], bvs[nt], accq[xx][nt]);

        // ---- epilogue: silu + v-gate per edge, then hierarchical aggregation ----
        float sv[4][4];     // [nt][reg]
        float gv[2][3][4];  // [h][xx][reg]
        #pragma unroll
        for (int reg=0; reg<4; reg++){
            int e2 = quad*4 + reg;
            float4 ev = sEv4[w][e2];
            float es = ev.w;
            float evx[3] = {ev.x, ev.y, ev.z};
            #pragma unroll
            for (int nt=0;nt<4;nt++)
                sv[nt][reg] = siluf(es*accss[nt][reg] + accvv[nt][reg]);
            float vals[2][3]; float part = 0.f;
            #pragma unroll
            for (int h=0;h<2;h++)
                #pragma unroll
                for (int xx=0;xx<3;xx++){
                    float vvv = accp[h][reg]*evx[xx] + es*accq[xx][h][reg];
                    vals[h][xx] = vvv; part += vvv;
                }
            part += __shfl_xor(part,1); part += __shfl_xor(part,2);
            part += __shfl_xor(part,4); part += __shfl_xor(part,8);
            float mean = part*(1.0f/96.0f);
            #pragma unroll
            for (int h=0;h<2;h++)
                #pragma unroll
                for (int xx=0;xx<3;xx++)
                    gv[h][xx][reg] = vals[h][xx]*sigm(mean*gwv[h][xx] + gbv[h][xx]);
        }
        int r0 = sRow[w][0], r15 = sRow[w][15];
        if (r0 == r15){
            #pragma unroll
            for (int nt=0;nt<4;nt++){
                float s = sv[nt][0]+sv[nt][1]+sv[nt][2]+sv[nt][3];
                s += __shfl_xor(s,16); s += __shfl_xor(s,32);
                if (quad==0) emit(r0, nt*16+col, s);
            }
            #pragma unroll
            for (int h=0;h<2;h++)
                #pragma unroll
                for (int xx=0;xx<3;xx++){
                    float s = gv[h][xx][0]+gv[h][xx][1]+gv[h][xx][2]+gv[h][xx][3];
                    s += __shfl_xor(s,16); s += __shfl_xor(s,32);
                    if (quad==0) emit(r0, 64 + (h*16+col)*3+xx, s);
                }
        } else {
            int rq[4];
            #pragma unroll
            for (int reg=0;reg<4;reg++) rq[reg] = sRow[w][quad*4+reg];
            bool c1 = rq[1]==rq[0], c2 = rq[2]==rq[1], c3 = rq[3]==rq[2];
            auto seg = [&](int f, float v0, float v1, float v2, float v3){
                float run = v0;
                if (c1) run += v1; else { emit(rq[0], f, run); run = v1; }
                if (c2) run += v2; else { emit(rq[1], f, run); run = v2; }
                if (c3) run += v3; else { emit(rq[2], f, run); run = v3; }
                emit(rq[3], f, run);
            };
            #pragma unroll
            for (int nt=0;nt<4;nt++)
                seg(nt*16+col, sv[nt][0], sv[nt][1], sv[nt][2], sv[nt][3]);
            #pragma unroll
            for (int h=0;h<2;h++)
                #pragma unroll
                for (int xx=0;xx<3;xx++)
                    seg(64 + (h*16+col)*3+xx, gv[h][xx][0], gv[h][xx][1], gv[h][xx][2], gv[h][xx][3]);
        }
        __syncthreads();
    }

    // ---- flush window to global (atomics; zeros skipped) ----
    int rlast = row_s[blockStart + 255];
    int nr = rlast - rfirst + 1; if (nr > 16) nr = 16;
    for (int i=t; i<nr*160; i+=256){
        float v = sAcc[i];
        if (v != 0.f){
            int rl = i/160, f = i - rl*160;
            int r = rfirst + rl;
            if (f < 64) atomicAdd(&a_s[(size_t)r*64 + f], v);
            else        atomicAdd(&a_v[(size_t)r*96 + f - 64], v);
        }
    }
}

// ---------------------------------------------------------------- u_s (K=5120 GEMM)
__global__ __launch_bounds__(256) void k_us(
        const float* __restrict__ ns, const float* __restrict__ nvv,
        const float* __restrict__ a_s, const float* __restrict__ a_v,
        const short* __restrict__ Wusst, float* __restrict__ ns_out)
{
    __shared__ __align__(16) float ns16[16*68];
    __shared__ __align__(16) float as16[16*68];
    __shared__ __align__(16) float nv16[16*100];
    __shared__ __align__(16) float av16[16*100];
    __shared__ __align__(16) short sA[16*1032];

    const int t = threadIdx.x;
    const int w = t>>6, lane = t&63, col = lane&15, quad = lane>>4;
    const int nb = blockIdx.x*16;

    for (int idx=t; idx<1024; idx+=256){ int nd = idx>>6, i = idx&63;
        ns16[nd*68+i] = ns[(size_t)(nb+nd)*64+i];
        as16[nd*68+i] = a_s[(size_t)(nb+nd)*64+i];
    }
    for (int idx=t; idx<1536; idx+=256){ int nd = idx/96, i = idx-nd*96;
        nv16[nd*100+i] = nvv[(size_t)(nb+nd)*96+i];
        av16[nd*100+i] = a_v[(size_t)(nb+nd)*96+i];
    }
    __syncthreads();

    f32x4 acc = {0.f,0.f,0.f,0.f};
    for (int c=0;c<5;c++){
        if (c) __syncthreads();
        if (c < 4){
            #pragma unroll
            for (int itg=0; itg<8; itg++){
                int rid = t + itg*256;
                int nd = rid & 15;
                int kk0 = (rid>>4)<<3;
                int i = (c<<4) + (kk0>>6);
                int j0 = kk0 & 63;
                float nsv = ns16[nd*68 + i];
                const float* ap = &as16[nd*68 + j0];
                float4 x0 = *(const float4*)ap;
                float4 x1 = *(const float4*)(ap+4);
                bfrag8 o8;
                o8[0]=f2bf(nsv*x0.x); o8[1]=f2bf(nsv*x0.y); o8[2]=f2bf(nsv*x0.z); o8[3]=f2bf(nsv*x0.w);
                o8[4]=f2bf(nsv*x1.x); o8[5]=f2bf(nsv*x1.y); o8[6]=f2bf(nsv*x1.z); o8[7]=f2bf(nsv*x1.w);
                *(bfrag8*)&sA[nd*1032 + kk0] = o8;
            }
        } else {
            #pragma unroll
            for (int itg=0; itg<8; itg++){
                int rid = t + itg*256;
                int nd = rid & 15;
                int kk0 = (rid>>4)<<3;
                int m = kk0>>5, n0 = kk0&31;
                float v0 = nv16[nd*100 + m*3];
                float v1 = nv16[nd*100 + m*3+1];
                float v2 = nv16[nd*100 + m*3+2];
                const float* vp = &av16[nd*100 + n0*3];
                float yf[24];
                #pragma unroll
                for (int a=0;a<6;a++){ float4 y = *(const float4*)(vp+4*a);
                    yf[4*a]=y.x; yf[4*a+1]=y.y; yf[4*a+2]=y.z; yf[4*a+3]=y.w; }
                bfrag8 o8;
                #pragma unroll
                for (int jj=0;jj<8;jj++)
                    o8[jj] = f2bf(v0*yf[jj*3] + v1*yf[jj*3+1] + v2*yf[jj*3+2]);
                *(bfrag8*)&sA[nd*1032 + kk0] = o8;
            }
        }
        __syncthreads();
        const short* bp = Wusst + (size_t)(w*16+col)*5120 + c*1024 + quad*8;
        #pragma unroll
        for (int s=0;s<32;s++){
            bfrag8 a = *(bfrag8*)&sA[col*1032 + s*32 + quad*8];
            bfrag8 b = *(const bfrag8*)(bp + s*32);
            acc = MFMA(a, b, acc);
        }
    }
    #pragma unroll
    for (int reg=0; reg<4; reg++){
        int nd = quad*4 + reg;
        int o = w*16 + col;
        ns_out[(size_t)(nb+nd)*64 + o] = ns16[nd*68 + o] + siluf(acc[reg]);
    }
}

// ---------------------------------------------------------------- u_v
__global__ __launch_bounds__(256) void k_uv(
        const float* __restrict__ ns, const float* __restrict__ nvv,
        const float* __restrict__ a_s, const float* __restrict__ a_v,
        const short* __restrict__ Wusvt, const short* __restrict__ Wuvst,
        const float* __restrict__ guw, const float* __restrict__ gub,
        float* __restrict__ nv_out)
{
    __shared__ __align__(16) short nsbf[16*72];
    __shared__ __align__(16) short asbf[16*72];
    __shared__ __align__(16) float nv16[16*100];
    __shared__ __align__(16) float av16[16*100];
    __shared__ float uvb[2][16][96];

    const int t = threadIdx.x;
    const int w = t>>6, lane = t&63, col = lane&15, quad = lane>>4;
    const int nb = blockIdx.x*16;

    for (int idx=t; idx<1024; idx+=256){ int nd = idx>>6, i = idx&63;
        nsbf[nd*72+i] = f2bf(ns[(size_t)(nb+nd)*64+i]);
        asbf[nd*72+i] = f2bf(a_s[(size_t)(nb+nd)*64+i]);
    }
    for (int idx=t; idx<1536; idx+=256){ int nd = idx/96, i = idx-nd*96;
        nv16[nd*100+i] = nvv[(size_t)(nb+nd)*96+i];
        av16[nd*100+i] = a_v[(size_t)(nb+nd)*96+i];
    }
    __syncthreads();

    const int h = w>>1, o0 = (w&1)*16;
    const short* src = h ? asbf : nsbf;
    bfrag8 a0 = *(bfrag8*)&src[col*72 + quad*8];
    bfrag8 a1 = *(bfrag8*)&src[col*72 + 32 + quad*8];
    const short* Bt = h ? Wuvst : Wusvt;
    const float* M  = h ? nv16 : av16;
    float uva[3][4] = {};
    for (int n=0;n<32;n++){
        f32x4 acc = {0.f,0.f,0.f,0.f};
        const short* bp = Bt + (size_t)((n<<5) + o0 + col)*64 + quad*8;
        bfrag8 b0 = *(const bfrag8*)(bp);
        bfrag8 b1 = *(const bfrag8*)(bp + 32);
        acc = MFMA(a0,b0,acc);
        acc = MFMA(a1,b1,acc);
        #pragma unroll
        for (int reg=0;reg<4;reg++){
            int nd = quad*4+reg;
            float m0 = M[nd*100 + n*3];
            float m1 = M[nd*100 + n*3+1];
            float m2 = M[nd*100 + n*3+2];
            uva[0][reg] += acc[reg]*m0;
            uva[1][reg] += acc[reg]*m1;
            uva[2][reg] += acc[reg]*m2;
        }
    }
    #pragma unroll
    for (int reg=0;reg<4;reg++){
        int nd = quad*4+reg;
        #pragma unroll
        for (int xx=0;xx<3;xx++)
            uvb[h][nd][(o0+col)*3+xx] = uva[xx][reg];
    }
    __syncthreads();
    {
        int nd = t>>4, j = t&15;
        float part = 0.f;
        #pragma unroll
        for (int kk=j; kk<96; kk+=16) part += uvb[0][nd][kk] + uvb[1][nd][kk];
        part += __shfl_xor(part,1); part += __shfl_xor(part,2);
        part += __shfl_xor(part,4); part += __shfl_xor(part,8);
        float mean = part*(1.0f/96.0f);
        #pragma unroll
        for (int q2=0;q2<6;q2++){
            int kk = j*6 + q2;
            float uv = uvb[0][nd][kk] + uvb[1][nd][kk];
            float g = sigm(mean*guw[kk] + gub[kk]);
            nv_out[(size_t)(nb+nd)*96 + kk] = nv16[nd*100+kk] + uv*g;
        }
    }
}

// ---------------------------------------------------------------- out = ns@Wout/8
__global__ __launch_bounds__(256) void k_out(const float* __restrict__ ns,
                                             const short* __restrict__ Woutt,
                                             float* __restrict__ outp)
{
    __shared__ __align__(16) short nsbf[16*72];
    const int t = threadIdx.x;
    const int w = t>>6, lane = t&63, col = lane&15, quad = lane>>4;
    const int nb = blockIdx.x*16;
    for (int idx=t; idx<1024; idx+=256){ int nd=idx>>6, i=idx&63;
        nsbf[nd*72+i] = f2bf(ns[(size_t)(nb+nd)*64+i]); }
    __syncthreads();
    bfrag8 a0 = *(bfrag8*)&nsbf[col*72 + quad*8];
    bfrag8 a1 = *(bfrag8*)&nsbf[col*72 + 32 + quad*8];
    #pragma unroll
    for (int nt=0;nt<4;nt++){
        int o = w*64 + nt*16 + col;
        const short* bp = Woutt + (size_t)o*64 + quad*8;
        bfrag8 b0 = *(const bfrag8*)bp;
        bfrag8 b1 = *(const bfrag8*)(bp+32);
        f32x4 acc = {0.f,0.f,0.f,0.f};
        acc = MFMA(a0,b0,acc);
        acc = MFMA(a1,b1,acc);
        #pragma unroll
        for (int reg=0;reg<4;reg++)
            outp[(size_t)(nb + quad*4+reg)*256 + o] = acc[reg];
    }
}

// ---------------------------------------------------------------- launch
extern "C" void kernel_launch(void* const* d_in, const int* in_sizes, int n_in,
                              void* d_out, int out_size, void* d_ws, size_t ws_size,
                              hipStream_t stream)
{
    const float* x     = (const float*)d_in[0];
    const float* eattr = (const float*)d_in[1];
    const float* Win   = (const float*)d_in[2];
    const float* Wout  = (const float*)d_in[3];
    const float* Wss   = (const float*)d_in[4];
    const float* Wvv0  = (const float*)d_in[5];
    const float* Wsv   = (const float*)d_in[6];
    const float* Wvs   = (const float*)d_in[7];
    const float* gmw   = (const float*)d_in[8];
    const float* gmb   = (const float*)d_in[9];
    const float* Wuss  = (const float*)d_in[10];
    const float* Wuvv  = (const float*)d_in[11];
    const float* Wusv  = (const float*)d_in[12];
    const float* Wuvs  = (const float*)d_in[13];
    const float* guw   = (const float*)d_in[14];
    const float* gub   = (const float*)d_in[15];
    const int*   eidx  = (const int*)d_in[16];
    float* outp = (float*)d_out;

    char* p = (char*)d_ws;
    float* ns_a = (float*)p; p += (size_t)N_NODES*64*4;
    float* ns_b = (float*)p; p += (size_t)N_NODES*64*4;
    float* nv_a = (float*)p; p += (size_t)N_NODES*96*4;
    float* nv_b = (float*)p; p += (size_t)N_NODES*96*4;
    float* a_s  = (float*)p; p += (size_t)N_NODES*64*4;   // a_s,a_v contiguous (one memset)
    float* a_v  = (float*)p; p += (size_t)N_NODES*96*4;
    int*   cnt    = (int*)p;   p += (size_t)N_NODES*4;
    int*   cursor = (int*)p;   p += (size_t)N_NODES*4;
    int*   col_s  = (int*)p;   p += (size_t)N_EDGES*4;
    int*   row_s  = (int*)p;   p += (size_t)N_EDGES*4;
    float4* ea_s  = (float4*)p; p += (size_t)N_EDGES*16;
    short* wp   = (short*)p;

    k_prep<<<3720, 256, 0, stream>>>(Wss,Wvv0,Wsv,Wvs,Wuss,Wuvv,Wusv,Wuvs,Wout,wp);
    hipMemsetAsync(nv_a, 0, (size_t)N_NODES*96*4, stream);
    hipMemsetAsync(cnt, 0, (size_t)N_NODES*4, stream);
    k_in<<<N_NODES/4, 256, 0, stream>>>(x, Win, ns_a);
    k_hist<<<N_EDGES/256, 256, 0, stream>>>(eidx, cnt);
    k_scan<<<1, 256, 0, stream>>>(cnt, cursor);
    k_scatter<<<N_EDGES/256, 256, 0, stream>>>(eidx, eattr, cursor, col_s, row_s, ea_s);

    for (int l=0;l<2;l++){
        const float* cns = l ? ns_b : ns_a;
        const float* cnv = l ? nv_b : nv_a;
        float* nns = l ? ns_a : ns_b;
        float* nnv = l ? nv_a : nv_b;
        hipMemsetAsync(a_s, 0, (size_t)N_NODES*(64+96)*4, stream);
        k_edge<<<N_EDGES/256, 256, 0, stream>>>(cns, cnv, col_s, row_s, ea_s,
                                         wp + (size_t)l*PREP_L,
                                         gmw + l*96, gmb + l*96, a_s, a_v);
        k_uv<<<N_NODES/16, 256, 0, stream>>>(cns, cnv, a_s, a_v,
                                             wp + (size_t)l*PREP_L + 336896,
                                             wp + (size_t)l*PREP_L + 402432,
                                             guw + l*96, gub + l*96, nnv);
        k_us<<<N_NODES/16, 256, 0, stream>>>(cns, cnv, a_s, a_v,
                                             wp + (size_t)l*PREP_L + 9216, nns);
    }
    k_out<<<N_NODES/16, 256, 0, stream>>>(ns_a, wp + (size_t)2*PREP_L, outp);
}

// Round 5
// 1485.787 us; speedup vs baseline: 1.0196x; 1.0196x over previous
//
#include <hip/hip_runtime.h>

#define N_NODES 32768
#define N_EDGES 1048576
#define PREP_L  467968   // prepped bf16 weights per layer

typedef short bfrag8 __attribute__((ext_vector_type(8)));
typedef float f32x4  __attribute__((ext_vector_type(4)));

#define MFMA(a,b,c) __builtin_amdgcn_mfma_f32_16x16x32_bf16(a,b,c,0,0,0)

__device__ __forceinline__ short f2bf(float f){
    unsigned u = __float_as_uint(f);
    u += 0x7fffu + ((u >> 16) & 1u);
    return (short)(u >> 16);
}
__device__ __forceinline__ float sigm(float x){ return 1.0f/(1.0f + __expf(-x)); }
__device__ __forceinline__ float siluf(float x){ return x * sigm(x); }

// ---------------------------------------------------------------- weight prep
__global__ void k_prep(const float* Wss, const float* Wvv0, const float* Wsv,
                       const float* Wvs, const float* Wuss, const float* Wuvv,
                       const float* Wusv, const float* Wuvs, const float* Wout,
                       short* wp)
{
    int idx = blockIdx.x*256 + threadIdx.x;
    const int total = 2*PREP_L + 16384;
    if (idx >= total) return;
    const float s_ss  = 0.0883883476483f;  // 1/(8*sqrt2)
    const float s_vv  = 0.0721687836487f;  // (1/sqrt3)/8
    const float s_sv  = 0.0883883476483f;
    const float s_vs  = 0.125f;
    const float s_uss = 0.0110485434560f;  // 1/(64*sqrt2)
    const float s_uvv = 0.0127577593310f;  // 1/(32*sqrt6)
    const float s_uvw = 0.015625f;         // 1/64
    float v;
    if (idx >= 2*PREP_L){
        int r = idx - 2*PREP_L; int o = r >> 6, i = r & 63;
        v = Wout[i*256 + o] * 0.125f;
    } else {
        int l = idx / PREP_L; int off = idx - l*PREP_L;
        if (off < 6144){ int o = off/96, k = off - o*96;
            v = (k < 64) ? Wss[l*4096 + k*64 + o]*s_ss
                         : Wvv0[l*2048 + (k-64)*64 + o]*s_vv;
        } else if (off < 8192){ int tt = off - 6144; int m = tt>>6, i = tt&63;
            v = Wsv[l*2048 + i*32 + m]*s_sv;
        } else if (off < 9216){ int tt = off - 8192; int n = tt>>5, m = tt&31;
            v = Wvs[l*1024 + m*32 + n]*s_vs;
        } else if (off < 336896){ int tt = off - 9216; int o = tt/5120, k = tt - o*5120;
            if (k < 4096) v = Wuss[l*262144 + k*64 + o]*s_uss;
            else          v = Wuvv[l*65536 + (k-4096)*64 + o]*s_uvv;
        } else if (off < 402432){ int tt = off - 336896; int nf = tt>>6, i = tt&63;
            int n = nf>>5, o = nf&31;
            v = Wusv[l*65536 + i*1024 + n*32 + o]*s_uvw;
        } else { int tt = off - 402432; int nf = tt>>6, j = tt&63;
            int m = nf>>5, o = nf&31;
            v = Wuvs[l*65536 + m*2048 + j*32 + o]*s_uvw;
        }
    }
    wp[idx] = f2bf(v);
}

// ---------------------------------------------------------------- ns = x@Win/8
__global__ void k_in(const float* __restrict__ x, const float* __restrict__ Win,
                     float* __restrict__ ns)
{
    int wv = threadIdx.x >> 6, o = threadIdx.x & 63;
    int node = blockIdx.x*4 + wv;
    const float* xr = x + (size_t)node*64;
    float acc = 0.f;
    #pragma unroll
    for (int i=0;i<64;i++) acc += xr[i]*Win[i*64+o];
    ns[(size_t)node*64+o] = 0.125f*acc;
}

// ---------------------------------------------------------------- sort: histogram
__global__ void k_hist(const int* __restrict__ eidx, int* __restrict__ cnt)
{
    int e = blockIdx.x*256 + threadIdx.x;
    atomicAdd(&cnt[eidx[e]], 1);
}

// ---------------------------------------------------------------- sort: scan (1 block)
__global__ void k_scan(const int* __restrict__ cnt, int* __restrict__ cursor)
{
    __shared__ int part[256];
    int t = threadIdx.x;
    int base = t*128;
    int s = 0;
    for (int i=0;i<128;i++) s += cnt[base+i];
    part[t] = s; __syncthreads();
    for (int off=1; off<256; off<<=1){
        int v = (t>=off) ? part[t-off] : 0;
        __syncthreads();
        part[t] += v;
        __syncthreads();
    }
    int run = part[t] - s;   // exclusive prefix
    for (int i=0;i<128;i++){ cursor[base+i] = run; run += cnt[base+i]; }
}

// ---------------------------------------------------------------- sort: scatter + pre-gather
__global__ void k_scatter(const int* __restrict__ eidx, const float* __restrict__ eattr,
                          int* __restrict__ cursor, int* __restrict__ col_s,
                          int* __restrict__ row_s, float4* __restrict__ ea_s)
{
    int e = blockIdx.x*256 + threadIdx.x;
    int r = eidx[e];
    int d = atomicAdd(&cursor[r], 1);
    row_s[d] = r;
    col_s[d] = eidx[N_EDGES + e];
    ea_s[d]  = ((const float4*)eattr)[e];
}

// ---------------------------------------------------------------- edge phase (sorted slots)
// __launch_bounds__(256,3): ~168-VGPR budget keeps all B-frags + accumulators
// resident (the (256,4)/64-VGPR variant spilled: +600MB FETCH, +287MB WRITE).
__global__ __launch_bounds__(256, 3) void k_edge(
        const float* __restrict__ ns, const float* __restrict__ nv,
        const int* __restrict__ col_s, const int* __restrict__ row_s,
        const float4* __restrict__ ea_s,
        const short* __restrict__ wp_l,
        const float* __restrict__ gmw, const float* __restrict__ gmb,
        float* __restrict__ a_s, float* __restrict__ a_v)
{
    __shared__ __align__(16) short sA1[4][16*36];    // tvv = hv.ev (K=32)
    __shared__ __align__(16) short sA2[4][16*72];    // raw hs (K=64)
    __shared__ __align__(16) short sAv[4][3*16*36];  // raw hv per x (K=32)
    __shared__ int    sRow[4][16];
    __shared__ float4 sEv4[4][16];                   // ev.xyz, es
    __shared__ float  sAcc[24*160];                  // row-window accumulator

    const int t = threadIdx.x;
    const int w = t >> 6, lane = t & 63;
    const int col = lane & 15, quad = lane >> 4;
    const int blockStart = blockIdx.x*256;
    const int rfirst = row_s[blockStart];

    for (int i=t; i<24*160; i+=256) sAcc[i] = 0.f;

    const short* W1t  = wp_l;
    const short* Wsvt = wp_l + 6144;
    const short* Wvst = wp_l + 8192;

    bfrag8 bss[2][4], bvv[4], bsv[2][2], bvs[2];
    #pragma unroll
    for (int s=0;s<2;s++)
        #pragma unroll
        for (int nt=0;nt<4;nt++)
            bss[s][nt] = *(const bfrag8*)(W1t + (nt*16+col)*96 + s*32 + quad*8);
    #pragma unroll
    for (int nt=0;nt<4;nt++)
        bvv[nt] = *(const bfrag8*)(W1t + (nt*16+col)*96 + 64 + quad*8);
    #pragma unroll
    for (int s=0;s<2;s++)
        #pragma unroll
        for (int nt=0;nt<2;nt++)
            bsv[s][nt] = *(const bfrag8*)(Wsvt + (nt*16+col)*64 + s*32 + quad*8);
    #pragma unroll
    for (int nt=0;nt<2;nt++)
        bvs[nt] = *(const bfrag8*)(Wvst + (nt*16+col)*32 + quad*8);

    float gwv[2][3], gbv[2][3];
    #pragma unroll
    for (int h=0;h<2;h++)
        #pragma unroll
        for (int xx=0;xx<3;xx++){
            int k = (h*16+col)*3+xx;
            gwv[h][xx] = gmw[k]; gbv[h][xx] = gmb[k];
        }

    auto emit = [&](int r, int f, float v){
        int rl = r - rfirst;
        if (rl < 24) atomicAdd(&sAcc[rl*160 + f], v);
        else if (f < 64) atomicAdd(&a_s[(size_t)r*64 + f], v);
        else             atomicAdd(&a_v[(size_t)r*96 + f - 64], v);
    };

    __syncthreads();

    for (int it=0; it<4; it++){
        int tileBase = blockStart + w*64 + it*16;
        { // ---- stage: lane (quad q, edge e) ----
            int e = col, q = quad;
            int sg = tileBase + e;
            int c = col_s[sg];
            float4 ea = ea_s[sg];
            const float* nsr = ns + (size_t)c*64 + q*16;
            float4 h4[4]; float hq[16];
            #pragma unroll
            for (int a=0;a<4;a++) h4[a] = *(const float4*)(nsr + 4*a);
            #pragma unroll
            for (int a=0;a<4;a++){ hq[4*a]=h4[a].x; hq[4*a+1]=h4[a].y; hq[4*a+2]=h4[a].z; hq[4*a+3]=h4[a].w; }
            const float* nvr = nv + (size_t)c*96 + q*24;
            float4 g4[6]; float hv[24];
            #pragma unroll
            for (int a=0;a<6;a++) g4[a] = *(const float4*)(nvr + 4*a);
            #pragma unroll
            for (int a=0;a<6;a++){ hv[4*a]=g4[a].x; hv[4*a+1]=g4[a].y; hv[4*a+2]=g4[a].z; hv[4*a+3]=g4[a].w; }
            #pragma unroll
            for (int hk=0; hk<2; hk++){
                bfrag8 vr;
                #pragma unroll
                for (int j=0;j<8;j++) vr[j] = f2bf(hq[hk*8+j]);
                *(bfrag8*)&sA2[w][e*72 + q*16 + hk*8] = vr;
            }
            bfrag8 vt;
            #pragma unroll
            for (int mi=0;mi<8;mi++)
                vt[mi] = f2bf(hv[mi*3]*ea.x + hv[mi*3+1]*ea.y + hv[mi*3+2]*ea.z);
            *(bfrag8*)&sA1[w][e*36 + q*8] = vt;
            #pragma unroll
            for (int xx=0;xx<3;xx++){
                bfrag8 vv;
                #pragma unroll
                for (int mi=0;mi<8;mi++) vv[mi] = f2bf(hv[mi*3+xx]);
                *(bfrag8*)&sAv[w][xx*576 + e*36 + q*8] = vv;
            }
            if (q==0){
                sRow[w][e] = row_s[sg];
                sEv4[w][e] = ea;
            }
        }
        __syncthreads();
        // ---- MFMA ----
        f32x4 accss[4], accvv[4], accp[2], accq[3][2];
        #pragma unroll
        for (int nt=0;nt<4;nt++){ accss[nt] = (f32x4){0.f,0.f,0.f,0.f};
                                  accvv[nt] = (f32x4){0.f,0.f,0.f,0.f}; }
        #pragma unroll
        for (int nt=0;nt<2;nt++) accp[nt] = (f32x4){0.f,0.f,0.f,0.f};
        #pragma unroll
        for (int xx=0;xx<3;xx++)
            #pragma unroll
            for (int nt=0;nt<2;nt++) accq[xx][nt] = (f32x4){0.f,0.f,0.f,0.f};
        bfrag8 a1, a2[2], av3[3];
        a1 = *(bfrag8*)&sA1[w][col*36 + quad*8];
        #pragma unroll
        for (int s=0;s<2;s++) a2[s] = *(bfrag8*)&sA2[w][col*72 + s*32 + quad*8];
        #pragma unroll
        for (int xx=0;xx<3;xx++) av3[xx] = *(bfrag8*)&sAv[w][xx*576 + col*36 + quad*8];
        #pragma unroll
        for (int s=0;s<2;s++)
            #pragma unroll
            for (int nt=0;nt<4;nt++) accss[nt] = MFMA(a2[s], bss[s][nt], accss[nt]);
        #pragma unroll
        for (int nt=0;nt<4;nt++) accvv[nt] = MFMA(a1, bvv[nt], accvv[nt]);
        #pragma unroll
        for (int s=0;s<2;s++)
            #pragma unroll
            for (int nt=0;nt<2;nt++) accp[nt] = MFMA(a2[s], bsv[s][nt], accp[nt]);
        #pragma unroll
        for (int xx=0;xx<3;xx++)
            #pragma unroll
            for (int nt=0;nt<2;nt++) accq[xx][nt] = MFMA(av3[xx], bvs[nt], accq[xx][nt]);

        // ---- epilogue: silu + v-gate per edge, then hierarchical aggregation ----
        float sv[4][4];     // [nt][reg]
        float gv[2][3][4];  // [h][xx][reg]
        #pragma unroll
        for (int reg=0; reg<4; reg++){
            int e2 = quad*4 + reg;
            float4 ev = sEv4[w][e2];
            float es = ev.w;
            float evx[3] = {ev.x, ev.y, ev.z};
            #pragma unroll
            for (int nt=0;nt<4;nt++)
                sv[nt][reg] = siluf(es*accss[nt][reg] + accvv[nt][reg]);
            float vals[2][3]; float part = 0.f;
            #pragma unroll
            for (int h=0;h<2;h++)
                #pragma unroll
                for (int xx=0;xx<3;xx++){
                    float vvv = accp[h][reg]*evx[xx] + es*accq[xx][h][reg];
                    vals[h][xx] = vvv; part += vvv;
                }
            part += __shfl_xor(part,1); part += __shfl_xor(part,2);
            part += __shfl_xor(part,4); part += __shfl_xor(part,8);
            float mean = part*(1.0f/96.0f);
            #pragma unroll
            for (int h=0;h<2;h++)
                #pragma unroll
                for (int xx=0;xx<3;xx++)
                    gv[h][xx][reg] = vals[h][xx]*sigm(mean*gwv[h][xx] + gbv[h][xx]);
        }
        int r0 = sRow[w][0], r15 = sRow[w][15];
        if (r0 == r15){
            #pragma unroll
            for (int nt=0;nt<4;nt++){
                float s = sv[nt][0]+sv[nt][1]+sv[nt][2]+sv[nt][3];
                s += __shfl_xor(s,16); s += __shfl_xor(s,32);
                if (quad==0) emit(r0, nt*16+col, s);
            }
            #pragma unroll
            for (int h=0;h<2;h++)
                #pragma unroll
                for (int xx=0;xx<3;xx++){
                    float s = gv[h][xx][0]+gv[h][xx][1]+gv[h][xx][2]+gv[h][xx][3];
                    s += __shfl_xor(s,16); s += __shfl_xor(s,32);
                    if (quad==0) emit(r0, 64 + (h*16+col)*3+xx, s);
                }
        } else {
            int rq[4];
            #pragma unroll
            for (int reg=0;reg<4;reg++) rq[reg] = sRow[w][quad*4+reg];
            bool c1 = rq[1]==rq[0], c2 = rq[2]==rq[1], c3 = rq[3]==rq[2];
            auto seg = [&](int f, float v0, float v1, float v2, float v3){
                float run = v0;
                if (c1) run += v1; else { emit(rq[0], f, run); run = v1; }
                if (c2) run += v2; else { emit(rq[1], f, run); run = v2; }
                if (c3) run += v3; else { emit(rq[2], f, run); run = v3; }
                emit(rq[3], f, run);
            };
            #pragma unroll
            for (int nt=0;nt<4;nt++)
                seg(nt*16+col, sv[nt][0], sv[nt][1], sv[nt][2], sv[nt][3]);
            #pragma unroll
            for (int h=0;h<2;h++)
                #pragma unroll
                for (int xx=0;xx<3;xx++)
                    seg(64 + (h*16+col)*3+xx, gv[h][xx][0], gv[h][xx][1], gv[h][xx][2], gv[h][xx][3]);
        }
        __syncthreads();
    }

    // ---- flush window to global (atomics; zeros skipped) ----
    int rlast = row_s[blockStart + 255];
    int nr = rlast - rfirst + 1; if (nr > 24) nr = 24;
    for (int i=t; i<nr*160; i+=256){
        float v = sAcc[i];
        if (v != 0.f){
            int rl = i/160, f = i - rl*160;
            int r = rfirst + rl;
            if (f < 64) atomicAdd(&a_s[(size_t)r*64 + f], v);
            else        atomicAdd(&a_v[(size_t)r*96 + f - 64], v);
        }
    }
}

// ---------------------------------------------------------------- u_s (K=5120 GEMM)
__global__ __launch_bounds__(256) void k_us(
        const float* __restrict__ ns, const float* __restrict__ nvv,
        const float* __restrict__ a_s, const float* __restrict__ a_v,
        const short* __restrict__ Wusst, float* __restrict__ ns_out)
{
    __shared__ __align__(16) float ns16[16*68];
    __shared__ __align__(16) float as16[16*68];
    __shared__ __align__(16) float nv16[16*100];
    __shared__ __align__(16) float av16[16*100];
    __shared__ __align__(16) short sA[16*1032];

    const int t = threadIdx.x;
    const int w = t>>6, lane = t&63, col = lane&15, quad = lane>>4;
    const int nb = blockIdx.x*16;

    for (int idx=t; idx<1024; idx+=256){ int nd = idx>>6, i = idx&63;
        ns16[nd*68+i] = ns[(size_t)(nb+nd)*64+i];
        as16[nd*68+i] = a_s[(size_t)(nb+nd)*64+i];
    }
    for (int idx=t; idx<1536; idx+=256){ int nd = idx/96, i = idx-nd*96;
        nv16[nd*100+i] = nvv[(size_t)(nb+nd)*96+i];
        av16[nd*100+i] = a_v[(size_t)(nb+nd)*96+i];
    }
    __syncthreads();

    f32x4 acc = {0.f,0.f,0.f,0.f};
    for (int c=0;c<5;c++){
        if (c) __syncthreads();
        if (c < 4){
            #pragma unroll
            for (int itg=0; itg<8; itg++){
                int rid = t + itg*256;
                int nd = rid & 15;
                int kk0 = (rid>>4)<<3;
                int i = (c<<4) + (kk0>>6);
                int j0 = kk0 & 63;
                float nsv = ns16[nd*68 + i];
                const float* ap = &as16[nd*68 + j0];
                float4 x0 = *(const float4*)ap;
                float4 x1 = *(const float4*)(ap+4);
                bfrag8 o8;
                o8[0]=f2bf(nsv*x0.x); o8[1]=f2bf(nsv*x0.y); o8[2]=f2bf(nsv*x0.z); o8[3]=f2bf(nsv*x0.w);
                o8[4]=f2bf(nsv*x1.x); o8[5]=f2bf(nsv*x1.y); o8[6]=f2bf(nsv*x1.z); o8[7]=f2bf(nsv*x1.w);
                *(bfrag8*)&sA[nd*1032 + kk0] = o8;
            }
        } else {
            #pragma unroll
            for (int itg=0; itg<8; itg++){
                int rid = t + itg*256;
                int nd = rid & 15;
                int kk0 = (rid>>4)<<3;
                int m = kk0>>5, n0 = kk0&31;
                float v0 = nv16[nd*100 + m*3];
                float v1 = nv16[nd*100 + m*3+1];
                float v2 = nv16[nd*100 + m*3+2];
                const float* vp = &av16[nd*100 + n0*3];
                float yf[24];
                #pragma unroll
                for (int a=0;a<6;a++){ float4 y = *(const float4*)(vp+4*a);
                    yf[4*a]=y.x; yf[4*a+1]=y.y; yf[4*a+2]=y.z; yf[4*a+3]=y.w; }
                bfrag8 o8;
                #pragma unroll
                for (int jj=0;jj<8;jj++)
                    o8[jj] = f2bf(v0*yf[jj*3] + v1*yf[jj*3+1] + v2*yf[jj*3+2]);
                *(bfrag8*)&sA[nd*1032 + kk0] = o8;
            }
        }
        __syncthreads();
        const short* bp = Wusst + (size_t)(w*16+col)*5120 + c*1024 + quad*8;
        #pragma unroll
        for (int s=0;s<32;s++){
            bfrag8 a = *(bfrag8*)&sA[col*1032 + s*32 + quad*8];
            bfrag8 b = *(const bfrag8*)(bp + s*32);
            acc = MFMA(a, b, acc);
        }
    }
    #pragma unroll
    for (int reg=0; reg<4; reg++){
        int nd = quad*4 + reg;
        int o = w*16 + col;
        ns_out[(size_t)(nb+nd)*64 + o] = ns16[nd*68 + o] + siluf(acc[reg]);
    }
}

// ---------------------------------------------------------------- u_v
__global__ __launch_bounds__(256) void k_uv(
        const float* __restrict__ ns, const float* __restrict__ nvv,
        const float* __restrict__ a_s, const float* __restrict__ a_v,
        const short* __restrict__ Wusvt, const short* __restrict__ Wuvst,
        const float* __restrict__ guw, const float* __restrict__ gub,
        float* __restrict__ nv_out)
{
    __shared__ __align__(16) short nsbf[16*72];
    __shared__ __align__(16) short asbf[16*72];
    __shared__ __align__(16) float nv16[16*100];
    __shared__ __align__(16) float av16[16*100];
    __shared__ float uvb[2][16][96];

    const int t = threadIdx.x;
    const int w = t>>6, lane = t&63, col = lane&15, quad = lane>>4;
    const int nb = blockIdx.x*16;

    for (int idx=t; idx<1024; idx+=256){ int nd = idx>>6, i = idx&63;
        nsbf[nd*72+i] = f2bf(ns[(size_t)(nb+nd)*64+i]);
        asbf[nd*72+i] = f2bf(a_s[(size_t)(nb+nd)*64+i]);
    }
    for (int idx=t; idx<1536; idx+=256){ int nd = idx/96, i = idx-nd*96;
        nv16[nd*100+i] = nvv[(size_t)(nb+nd)*96+i];
        av16[nd*100+i] = a_v[(size_t)(nb+nd)*96+i];
    }
    __syncthreads();

    const int h = w>>1, o0 = (w&1)*16;
    const short* src = h ? asbf : nsbf;
    bfrag8 a0 = *(bfrag8*)&src[col*72 + quad*8];
    bfrag8 a1 = *(bfrag8*)&src[col*72 + 32 + quad*8];
    const short* Bt = h ? Wuvst : Wusvt;
    const float* M  = h ? nv16 : av16;
    float uva[3][4] = {};
    for (int n=0;n<32;n++){
        f32x4 acc = {0.f,0.f,0.f,0.f};
        const short* bp = Bt + (size_t)((n<<5) + o0 + col)*64 + quad*8;
        bfrag8 b0 = *(const bfrag8*)(bp);
        bfrag8 b1 = *(const bfrag8*)(bp + 32);
        acc = MFMA(a0,b0,acc);
        acc = MFMA(a1,b1,acc);
        #pragma unroll
        for (int reg=0;reg<4;reg++){
            int nd = quad*4+reg;
            float m0 = M[nd*100 + n*3];
            float m1 = M[nd*100 + n*3+1];
            float m2 = M[nd*100 + n*3+2];
            uva[0][reg] += acc[reg]*m0;
            uva[1][reg] += acc[reg]*m1;
            uva[2][reg] += acc[reg]*m2;
        }
    }
    #pragma unroll
    for (int reg=0;reg<4;reg++){
        int nd = quad*4+reg;
        #pragma unroll
        for (int xx=0;xx<3;xx++)
            uvb[h][nd][(o0+col)*3+xx] = uva[xx][reg];
    }
    __syncthreads();
    {
        int nd = t>>4, j = t&15;
        float part = 0.f;
        #pragma unroll
        for (int kk=j; kk<96; kk+=16) part += uvb[0][nd][kk] + uvb[1][nd][kk];
        part += __shfl_xor(part,1); part += __shfl_xor(part,2);
        part += __shfl_xor(part,4); part += __shfl_xor(part,8);
        float mean = part*(1.0f/96.0f);
        #pragma unroll
        for (int q2=0;q2<6;q2++){
            int kk = j*6 + q2;
            float uv = uvb[0][nd][kk] + uvb[1][nd][kk];
            float g = sigm(mean*guw[kk] + gub[kk]);
            nv_out[(size_t)(nb+nd)*96 + kk] = nv16[nd*100+kk] + uv*g;
        }
    }
}

// ---------------------------------------------------------------- out = ns@Wout/8
__global__ __launch_bounds__(256) void k_out(const float* __restrict__ ns,
                                             const short* __restrict__ Woutt,
                                             float* __restrict__ outp)
{
    __shared__ __align__(16) short nsbf[16*72];
    const int t = threadIdx.x;
    const int w = t>>6, lane = t&63, col = lane&15, quad = lane>>4;
    const int nb = blockIdx.x*16;
    for (int idx=t; idx<1024; idx+=256){ int nd=idx>>6, i=idx&63;
        nsbf[nd*72+i] = f2bf(ns[(size_t)(nb+nd)*64+i]); }
    __syncthreads();
    bfrag8 a0 = *(bfrag8*)&nsbf[col*72 + quad*8];
    bfrag8 a1 = *(bfrag8*)&nsbf[col*72 + 32 + quad*8];
    #pragma unroll
    for (int nt=0;nt<4;nt++){
        int o = w*64 + nt*16 + col;
        const short* bp = Woutt + (size_t)o*64 + quad*8;
        bfrag8 b0 = *(const bfrag8*)bp;
        bfrag8 b1 = *(const bfrag8*)(bp+32);
        f32x4 acc = {0.f,0.f,0.f,0.f};
        acc = MFMA(a0,b0,acc);
        acc = MFMA(a1,b1,acc);
        #pragma unroll
        for (int reg=0;reg<4;reg++)
            outp[(size_t)(nb + quad*4+reg)*256 + o] = acc[reg];
    }
}

// ---------------------------------------------------------------- launch
extern "C" void kernel_launch(void* const* d_in, const int* in_sizes, int n_in,
                              void* d_out, int out_size, void* d_ws, size_t ws_size,
                              hipStream_t stream)
{
    const float* x     = (const float*)d_in[0];
    const float* eattr = (const float*)d_in[1];
    const float* Win   = (const float*)d_in[2];
    const float* Wout  = (const float*)d_in[3];
    const float* Wss   = (const float*)d_in[4];
    const float* Wvv0  = (const float*)d_in[5];
    const float* Wsv   = (const float*)d_in[6];
    const float* Wvs   = (const float*)d_in[7];
    const float* gmw   = (const float*)d_in[8];
    const float* gmb   = (const float*)d_in[9];
    const float* Wuss  = (const float*)d_in[10];
    const float* Wuvv  = (const float*)d_in[11];
    const float* Wusv  = (const float*)d_in[12];
    const float* Wuvs  = (const float*)d_in[13];
    const float* guw   = (const float*)d_in[14];
    const float* gub   = (const float*)d_in[15];
    const int*   eidx  = (const int*)d_in[16];
    float* outp = (float*)d_out;

    char* p = (char*)d_ws;
    float* ns_a = (float*)p; p += (size_t)N_NODES*64*4;
    float* ns_b = (float*)p; p += (size_t)N_NODES*64*4;
    float* nv_a = (float*)p; p += (size_t)N_NODES*96*4;
    float* nv_b = (float*)p; p += (size_t)N_NODES*96*4;
    float* a_s  = (float*)p; p += (size_t)N_NODES*64*4;   // a_s,a_v contiguous (one memset)
    float* a_v  = (float*)p; p += (size_t)N_NODES*96*4;
    int*   cnt    = (int*)p;   p += (size_t)N_NODES*4;
    int*   cursor = (int*)p;   p += (size_t)N_NODES*4;
    int*   col_s  = (int*)p;   p += (size_t)N_EDGES*4;
    int*   row_s  = (int*)p;   p += (size_t)N_EDGES*4;
    float4* ea_s  = (float4*)p; p += (size_t)N_EDGES*16;
    short* wp   = (short*)p;

    k_prep<<<3720, 256, 0, stream>>>(Wss,Wvv0,Wsv,Wvs,Wuss,Wuvv,Wusv,Wuvs,Wout,wp);
    hipMemsetAsync(nv_a, 0, (size_t)N_NODES*96*4, stream);
    hipMemsetAsync(cnt, 0, (size_t)N_NODES*4, stream);
    k_in<<<N_NODES/4, 256, 0, stream>>>(x, Win, ns_a);
    k_hist<<<N_EDGES/256, 256, 0, stream>>>(eidx, cnt);
    k_scan<<<1, 256, 0, stream>>>(cnt, cursor);
    k_scatter<<<N_EDGES/256, 256, 0, stream>>>(eidx, eattr, cursor, col_s, row_s, ea_s);

    for (int l=0;l<2;l++){
        const float* cns = l ? ns_b : ns_a;
        const float* cnv = l ? nv_b : nv_a;
        float* nns = l ? ns_a : ns_b;
        float* nnv = l ? nv_a : nv_b;
        hipMemsetAsync(a_s, 0, (size_t)N_NODES*(64+96)*4, stream);
        k_edge<<<N_EDGES/256, 256, 0, stream>>>(cns, cnv, col_s, row_s, ea_s,
                                         wp + (size_t)l*PREP_L,
                                         gmw + l*96, gmb + l*96, a_s, a_v);
        k_uv<<<N_NODES/16, 256, 0, stream>>>(cns, cnv, a_s, a_v,
                                             wp + (size_t)l*PREP_L + 336896,
                                             wp + (size_t)l*PREP_L + 402432,
                                             guw + l*96, gub + l*96, nnv);
        k_us<<<N_NODES/16, 256, 0, stream>>>(cns, cnv, a_s, a_v,
                                             wp + (size_t)l*PREP_L + 9216, nns);
    }
    k_out<<<N_NODES/16, 256, 0, stream>>>(ns_a, wp + (size_t)2*PREP_L, outp);
}

// Round 6
// 1418.162 us; speedup vs baseline: 1.0682x; 1.0477x over previous
//
#include <hip/hip_runtime.h>

#define N_NODES 32768
#define N_EDGES 1048576
#define PREP_L  467968   // prepped bf16 weights per layer

typedef short bfrag8 __attribute__((ext_vector_type(8)));
typedef float f32x4  __attribute__((ext_vector_type(4)));

#define MFMA(a,b,c) __builtin_amdgcn_mfma_f32_16x16x32_bf16(a,b,c,0,0,0)

__device__ __forceinline__ short f2bf(float f){
    unsigned u = __float_as_uint(f);
    u += 0x7fffu + ((u >> 16) & 1u);
    return (short)(u >> 16);
}
__device__ __forceinline__ float sigm(float x){ return 1.0f/(1.0f + __expf(-x)); }
__device__ __forceinline__ float siluf(float x){ return x * sigm(x); }

// ---------------------------------------------------------------- weight prep
__global__ void k_prep(const float* Wss, const float* Wvv0, const float* Wsv,
                       const float* Wvs, const float* Wuss, const float* Wuvv,
                       const float* Wusv, const float* Wuvs, const float* Wout,
                       short* wp)
{
    int idx = blockIdx.x*256 + threadIdx.x;
    const int total = 2*PREP_L + 16384;
    if (idx >= total) return;
    const float s_ss  = 0.0883883476483f;  // 1/(8*sqrt2)
    const float s_vv  = 0.0721687836487f;  // (1/sqrt3)/8
    const float s_sv  = 0.0883883476483f;
    const float s_vs  = 0.125f;
    const float s_uss = 0.0110485434560f;  // 1/(64*sqrt2)
    const float s_uvv = 0.0127577593310f;  // 1/(32*sqrt6)
    const float s_uvw = 0.015625f;         // 1/64
    float v;
    if (idx >= 2*PREP_L){
        int r = idx - 2*PREP_L; int o = r >> 6, i = r & 63;
        v = Wout[i*256 + o] * 0.125f;
    } else {
        int l = idx / PREP_L; int off = idx - l*PREP_L;
        if (off < 6144){ int o = off/96, k = off - o*96;
            v = (k < 64) ? Wss[l*4096 + k*64 + o]*s_ss
                         : Wvv0[l*2048 + (k-64)*64 + o]*s_vv;
        } else if (off < 8192){ int tt = off - 6144; int m = tt>>6, i = tt&63;
            v = Wsv[l*2048 + i*32 + m]*s_sv;
        } else if (off < 9216){ int tt = off - 8192; int n = tt>>5, m = tt&31;
            v = Wvs[l*1024 + m*32 + n]*s_vs;
        } else if (off < 336896){ int tt = off - 9216; int o = tt/5120, k = tt - o*5120;
            if (k < 4096) v = Wuss[l*262144 + k*64 + o]*s_uss;
            else          v = Wuvv[l*65536 + (k-4096)*64 + o]*s_uvv;
        } else if (off < 402432){ int tt = off - 336896; int nf = tt>>6, i = tt&63;
            int n = nf>>5, o = nf&31;
            v = Wusv[l*65536 + i*1024 + n*32 + o]*s_uvw;
        } else { int tt = off - 402432; int nf = tt>>6, j = tt&63;
            int m = nf>>5, o = nf&31;
            v = Wuvs[l*65536 + m*2048 + j*32 + o]*s_uvw;
        }
    }
    wp[idx] = f2bf(v);
}

// ---------------------------------------------------------------- ns = x@Win/8
__global__ void k_in(const float* __restrict__ x, const float* __restrict__ Win,
                     float* __restrict__ ns)
{
    int wv = threadIdx.x >> 6, o = threadIdx.x & 63;
    int node = blockIdx.x*4 + wv;
    const float* xr = x + (size_t)node*64;
    float acc = 0.f;
    #pragma unroll
    for (int i=0;i<64;i++) acc += xr[i]*Win[i*64+o];
    ns[(size_t)node*64+o] = 0.125f*acc;
}

// ---------------------------------------------------------------- sort: histogram
__global__ void k_hist(const int* __restrict__ eidx, int* __restrict__ cnt)
{
    int e = blockIdx.x*256 + threadIdx.x;
    atomicAdd(&cnt[eidx[e]], 1);
}

// ---------------------------------------------------------------- sort: scan (1 block)
__global__ void k_scan(const int* __restrict__ cnt, int* __restrict__ cursor)
{
    __shared__ int part[256];
    int t = threadIdx.x;
    int base = t*128;
    int s = 0;
    for (int i=0;i<128;i++) s += cnt[base+i];
    part[t] = s; __syncthreads();
    for (int off=1; off<256; off<<=1){
        int v = (t>=off) ? part[t-off] : 0;
        __syncthreads();
        part[t] += v;
        __syncthreads();
    }
    int run = part[t] - s;   // exclusive prefix
    for (int i=0;i<128;i++){ cursor[base+i] = run; run += cnt[base+i]; }
}

// ---------------------------------------------------------------- sort: scatter + pre-gather
__global__ void k_scatter(const int* __restrict__ eidx, const float* __restrict__ eattr,
                          int* __restrict__ cursor, int* __restrict__ col_s,
                          int* __restrict__ row_s, float4* __restrict__ ea_s)
{
    int e = blockIdx.x*256 + threadIdx.x;
    int r = eidx[e];
    int d = atomicAdd(&cursor[r], 1);
    row_s[d] = r;
    col_s[d] = eidx[N_EDGES + e];
    ea_s[d]  = ((const float4*)eattr)[e];
}

// ---------------------------------------------------------------- edge phase (sorted slots)
// Register-lean epilogue: gate means in a recompute pass, emits 4 values at a
// time. Peak live ~165 regs -> fits the (256,3) budget (~170) without spill.
__global__ __launch_bounds__(256, 3) void k_edge(
        const float* __restrict__ ns, const float* __restrict__ nv,
        const int* __restrict__ col_s, const int* __restrict__ row_s,
        const float4* __restrict__ ea_s,
        const short* __restrict__ wp_l,
        const float* __restrict__ gmw, const float* __restrict__ gmb,
        float* __restrict__ a_s, float* __restrict__ a_v)
{
    __shared__ __align__(16) short sA1[4][16*36];    // tvv = hv.ev (K=32)
    __shared__ __align__(16) short sA2[4][16*72];    // raw hs (K=64)
    __shared__ __align__(16) short sAv[4][3*16*36];  // raw hv per x (K=32)
    __shared__ int    sRow[4][16];
    __shared__ float4 sEv4[4][16];                   // ev.xyz, es
    __shared__ float  sAcc[24*160];                  // row-window accumulator

    const int t = threadIdx.x;
    const int w = t >> 6, lane = t & 63;
    const int col = lane & 15, quad = lane >> 4;
    const int blockStart = blockIdx.x*256;
    const int rfirst = row_s[blockStart];

    for (int i=t; i<24*160; i+=256) sAcc[i] = 0.f;

    const short* W1t  = wp_l;
    const short* Wsvt = wp_l + 6144;
    const short* Wvst = wp_l + 8192;

    bfrag8 bss[2][4], bvv[4], bsv[2][2], bvs[2];
    #pragma unroll
    for (int s=0;s<2;s++)
        #pragma unroll
        for (int nt=0;nt<4;nt++)
            bss[s][nt] = *(const bfrag8*)(W1t + (nt*16+col)*96 + s*32 + quad*8);
    #pragma unroll
    for (int nt=0;nt<4;nt++)
        bvv[nt] = *(const bfrag8*)(W1t + (nt*16+col)*96 + 64 + quad*8);
    #pragma unroll
    for (int s=0;s<2;s++)
        #pragma unroll
        for (int nt=0;nt<2;nt++)
            bsv[s][nt] = *(const bfrag8*)(Wsvt + (nt*16+col)*64 + s*32 + quad*8);
    #pragma unroll
    for (int nt=0;nt<2;nt++)
        bvs[nt] = *(const bfrag8*)(Wvst + (nt*16+col)*32 + quad*8);

    float gwv[2][3], gbv[2][3];
    #pragma unroll
    for (int h=0;h<2;h++)
        #pragma unroll
        for (int xx=0;xx<3;xx++){
            int k = (h*16+col)*3+xx;
            gwv[h][xx] = gmw[k]; gbv[h][xx] = gmb[k];
        }

    auto emit = [&](int r, int f, float v){
        int rl = r - rfirst;
        if (rl < 24) atomicAdd(&sAcc[rl*160 + f], v);
        else if (f < 64) atomicAdd(&a_s[(size_t)r*64 + f], v);
        else             atomicAdd(&a_v[(size_t)r*96 + f - 64], v);
    };

    __syncthreads();

    for (int it=0; it<4; it++){
        int tileBase = blockStart + w*64 + it*16;
        { // ---- stage: lane (quad q, edge e) ----
            int e = col, q = quad;
            int sg = tileBase + e;
            int c = col_s[sg];
            float4 ea = ea_s[sg];
            const float* nsr = ns + (size_t)c*64 + q*16;
            float4 h4[4]; float hq[16];
            #pragma unroll
            for (int a=0;a<4;a++) h4[a] = *(const float4*)(nsr + 4*a);
            #pragma unroll
            for (int a=0;a<4;a++){ hq[4*a]=h4[a].x; hq[4*a+1]=h4[a].y; hq[4*a+2]=h4[a].z; hq[4*a+3]=h4[a].w; }
            const float* nvr = nv + (size_t)c*96 + q*24;
            float4 g4[6]; float hv[24];
            #pragma unroll
            for (int a=0;a<6;a++) g4[a] = *(const float4*)(nvr + 4*a);
            #pragma unroll
            for (int a=0;a<6;a++){ hv[4*a]=g4[a].x; hv[4*a+1]=g4[a].y; hv[4*a+2]=g4[a].z; hv[4*a+3]=g4[a].w; }
            #pragma unroll
            for (int hk=0; hk<2; hk++){
                bfrag8 vr;
                #pragma unroll
                for (int j=0;j<8;j++) vr[j] = f2bf(hq[hk*8+j]);
                *(bfrag8*)&sA2[w][e*72 + q*16 + hk*8] = vr;
            }
            bfrag8 vt;
            #pragma unroll
            for (int mi=0;mi<8;mi++)
                vt[mi] = f2bf(hv[mi*3]*ea.x + hv[mi*3+1]*ea.y + hv[mi*3+2]*ea.z);
            *(bfrag8*)&sA1[w][e*36 + q*8] = vt;
            #pragma unroll
            for (int xx=0;xx<3;xx++){
                bfrag8 vv;
                #pragma unroll
                for (int mi=0;mi<8;mi++) vv[mi] = f2bf(hv[mi*3+xx]);
                *(bfrag8*)&sAv[w][xx*576 + e*36 + q*8] = vv;
            }
            if (q==0){
                sRow[w][e] = row_s[sg];
                sEv4[w][e] = ea;
            }
        }
        __syncthreads();
        // ---- MFMA ----
        f32x4 accss[4], accvv[4], accp[2], accq[3][2];
        #pragma unroll
        for (int nt=0;nt<4;nt++){ accss[nt] = (f32x4){0.f,0.f,0.f,0.f};
                                  accvv[nt] = (f32x4){0.f,0.f,0.f,0.f}; }
        #pragma unroll
        for (int nt=0;nt<2;nt++) accp[nt] = (f32x4){0.f,0.f,0.f,0.f};
        #pragma unroll
        for (int xx=0;xx<3;xx++)
            #pragma unroll
            for (int nt=0;nt<2;nt++) accq[xx][nt] = (f32x4){0.f,0.f,0.f,0.f};
        {
            bfrag8 a1 = *(bfrag8*)&sA1[w][col*36 + quad*8];
            bfrag8 a20 = *(bfrag8*)&sA2[w][col*72 + quad*8];
            bfrag8 a21 = *(bfrag8*)&sA2[w][col*72 + 32 + quad*8];
            #pragma unroll
            for (int nt=0;nt<4;nt++) accss[nt] = MFMA(a20, bss[0][nt], accss[nt]);
            #pragma unroll
            for (int nt=0;nt<4;nt++) accss[nt] = MFMA(a21, bss[1][nt], accss[nt]);
            #pragma unroll
            for (int nt=0;nt<4;nt++) accvv[nt] = MFMA(a1, bvv[nt], accvv[nt]);
            #pragma unroll
            for (int nt=0;nt<2;nt++) accp[nt] = MFMA(a20, bsv[0][nt], accp[nt]);
            #pragma unroll
            for (int nt=0;nt<2;nt++) accp[nt] = MFMA(a21, bsv[1][nt], accp[nt]);
            #pragma unroll
            for (int xx=0;xx<3;xx++){
                bfrag8 av = *(bfrag8*)&sAv[w][xx*576 + col*36 + quad*8];
                #pragma unroll
                for (int nt=0;nt<2;nt++) accq[xx][nt] = MFMA(av, bvs[nt], accq[xx][nt]);
            }
        }

        // ---- epilogue v2 (register-lean): pass 1 = gate means, pass 2 = emits
        float4 ev4[4];
        #pragma unroll
        for (int reg=0;reg<4;reg++) ev4[reg] = sEv4[w][quad*4+reg];
        float mean[4];
        #pragma unroll
        for (int reg=0;reg<4;reg++){
            float es = ev4[reg].w;
            float part = 0.f;
            #pragma unroll
            for (int h=0;h<2;h++){
                part += accp[h][reg]*ev4[reg].x + es*accq[0][h][reg];
                part += accp[h][reg]*ev4[reg].y + es*accq[1][h][reg];
                part += accp[h][reg]*ev4[reg].z + es*accq[2][h][reg];
            }
            part += __shfl_xor(part,1); part += __shfl_xor(part,2);
            part += __shfl_xor(part,4); part += __shfl_xor(part,8);
            mean[reg] = part*(1.0f/96.0f);
        }

        int r0 = sRow[w][0], r15 = sRow[w][15];
        bool uni = (r0 == r15);
        int rq[4];
        #pragma unroll
        for (int reg=0;reg<4;reg++) rq[reg] = sRow[w][quad*4+reg];
        bool c1 = rq[1]==rq[0], c2 = rq[2]==rq[1], c3 = rq[3]==rq[2];
        auto out4 = [&](int f, float v0, float v1, float v2, float v3){
            if (uni){
                float s = v0+v1+v2+v3;
                s += __shfl_xor(s,16); s += __shfl_xor(s,32);
                if (quad==0) emit(r0, f, s);
            } else {
                float run = v0;
                if (c1) run += v1; else { emit(rq[0], f, run); run = v1; }
                if (c2) run += v2; else { emit(rq[1], f, run); run = v2; }
                if (c3) run += v3; else { emit(rq[2], f, run); run = v3; }
                emit(rq[3], f, run);
            }
        };
        #pragma unroll
        for (int nt=0;nt<4;nt++){
            float v[4];
            #pragma unroll
            for (int reg=0;reg<4;reg++)
                v[reg] = siluf(ev4[reg].w*accss[nt][reg] + accvv[nt][reg]);
            out4(nt*16+col, v[0], v[1], v[2], v[3]);
        }
        #pragma unroll
        for (int h=0;h<2;h++)
            #pragma unroll
            for (int xx=0;xx<3;xx++){
                float v[4];
                #pragma unroll
                for (int reg=0;reg<4;reg++){
                    float evx = (xx==0) ? ev4[reg].x : ((xx==1) ? ev4[reg].y : ev4[reg].z);
                    float val = accp[h][reg]*evx + ev4[reg].w*accq[xx][h][reg];
                    v[reg] = val * sigm(mean[reg]*gwv[h][xx] + gbv[h][xx]);
                }
                out4(64 + (h*16+col)*3+xx, v[0], v[1], v[2], v[3]);
            }
        __syncthreads();
    }

    // ---- flush window to global (atomics; zeros skipped) ----
    int rlast = row_s[blockStart + 255];
    int nr = rlast - rfirst + 1; if (nr > 24) nr = 24;
    for (int i=t; i<nr*160; i+=256){
        float v = sAcc[i];
        if (v != 0.f){
            int rl = i/160, f = i - rl*160;
            int r = rfirst + rl;
            if (f < 64) atomicAdd(&a_s[(size_t)r*64 + f], v);
            else        atomicAdd(&a_v[(size_t)r*96 + f - 64], v);
        }
    }
}

// ---------------------------------------------------------------- u_s (K=5120 GEMM)
__global__ __launch_bounds__(256) void k_us(
        const float* __restrict__ ns, const float* __restrict__ nvv,
        const float* __restrict__ a_s, const float* __restrict__ a_v,
        const short* __restrict__ Wusst, float* __restrict__ ns_out)
{
    __shared__ __align__(16) float ns16[16*68];
    __shared__ __align__(16) float as16[16*68];
    __shared__ __align__(16) float nv16[16*100];
    __shared__ __align__(16) float av16[16*100];
    __shared__ __align__(16) short sA[16*1032];

    const int t = threadIdx.x;
    const int w = t>>6, lane = t&63, col = lane&15, quad = lane>>4;
    const int nb = blockIdx.x*16;

    for (int idx=t; idx<1024; idx+=256){ int nd = idx>>6, i = idx&63;
        ns16[nd*68+i] = ns[(size_t)(nb+nd)*64+i];
        as16[nd*68+i] = a_s[(size_t)(nb+nd)*64+i];
    }
    for (int idx=t; idx<1536; idx+=256){ int nd = idx/96, i = idx-nd*96;
        nv16[nd*100+i] = nvv[(size_t)(nb+nd)*96+i];
        av16[nd*100+i] = a_v[(size_t)(nb+nd)*96+i];
    }
    __syncthreads();

    f32x4 acc = {0.f,0.f,0.f,0.f};
    for (int c=0;c<5;c++){
        if (c) __syncthreads();
        if (c < 4){
            #pragma unroll
            for (int itg=0; itg<8; itg++){
                int rid = t + itg*256;
                int nd = rid & 15;
                int kk0 = (rid>>4)<<3;
                int i = (c<<4) + (kk0>>6);
                int j0 = kk0 & 63;
                float nsv = ns16[nd*68 + i];
                const float* ap = &as16[nd*68 + j0];
                float4 x0 = *(const float4*)ap;
                float4 x1 = *(const float4*)(ap+4);
                bfrag8 o8;
                o8[0]=f2bf(nsv*x0.x); o8[1]=f2bf(nsv*x0.y); o8[2]=f2bf(nsv*x0.z); o8[3]=f2bf(nsv*x0.w);
                o8[4]=f2bf(nsv*x1.x); o8[5]=f2bf(nsv*x1.y); o8[6]=f2bf(nsv*x1.z); o8[7]=f2bf(nsv*x1.w);
                *(bfrag8*)&sA[nd*1032 + kk0] = o8;
            }
        } else {
            #pragma unroll
            for (int itg=0; itg<8; itg++){
                int rid = t + itg*256;
                int nd = rid & 15;
                int kk0 = (rid>>4)<<3;
                int m = kk0>>5, n0 = kk0&31;
                float v0 = nv16[nd*100 + m*3];
                float v1 = nv16[nd*100 + m*3+1];
                float v2 = nv16[nd*100 + m*3+2];
                const float* vp = &av16[nd*100 + n0*3];
                float yf[24];
                #pragma unroll
                for (int a=0;a<6;a++){ float4 y = *(const float4*)(vp+4*a);
                    yf[4*a]=y.x; yf[4*a+1]=y.y; yf[4*a+2]=y.z; yf[4*a+3]=y.w; }
                bfrag8 o8;
                #pragma unroll
                for (int jj=0;jj<8;jj++)
                    o8[jj] = f2bf(v0*yf[jj*3] + v1*yf[jj*3+1] + v2*yf[jj*3+2]);
                *(bfrag8*)&sA[nd*1032 + kk0] = o8;
            }
        }
        __syncthreads();
        const short* bp = Wusst + (size_t)(w*16+col)*5120 + c*1024 + quad*8;
        #pragma unroll
        for (int s=0;s<32;s++){
            bfrag8 a = *(bfrag8*)&sA[col*1032 + s*32 + quad*8];
            bfrag8 b = *(const bfrag8*)(bp + s*32);
            acc = MFMA(a, b, acc);
        }
    }
    #pragma unroll
    for (int reg=0; reg<4; reg++){
        int nd = quad*4 + reg;
        int o = w*16 + col;
        ns_out[(size_t)(nb+nd)*64 + o] = ns16[nd*68 + o] + siluf(acc[reg]);
    }
}

// ---------------------------------------------------------------- u_v
__global__ __launch_bounds__(256) void k_uv(
        const float* __restrict__ ns, const float* __restrict__ nvv,
        const float* __restrict__ a_s, const float* __restrict__ a_v,
        const short* __restrict__ Wusvt, const short* __restrict__ Wuvst,
        const float* __restrict__ guw, const float* __restrict__ gub,
        float* __restrict__ nv_out)
{
    __shared__ __align__(16) short nsbf[16*72];
    __shared__ __align__(16) short asbf[16*72];
    __shared__ __align__(16) float nv16[16*100];
    __shared__ __align__(16) float av16[16*100];
    __shared__ float uvb[2][16][96];

    const int t = threadIdx.x;
    const int w = t>>6, lane = t&63, col = lane&15, quad = lane>>4;
    const int nb = blockIdx.x*16;

    for (int idx=t; idx<1024; idx+=256){ int nd = idx>>6, i = idx&63;
        nsbf[nd*72+i] = f2bf(ns[(size_t)(nb+nd)*64+i]);
        asbf[nd*72+i] = f2bf(a_s[(size_t)(nb+nd)*64+i]);
    }
    for (int idx=t; idx<1536; idx+=256){ int nd = idx/96, i = idx-nd*96;
        nv16[nd*100+i] = nvv[(size_t)(nb+nd)*96+i];
        av16[nd*100+i] = a_v[(size_t)(nb+nd)*96+i];
    }
    __syncthreads();

    const int h = w>>1, o0 = (w&1)*16;
    const short* src = h ? asbf : nsbf;
    bfrag8 a0 = *(bfrag8*)&src[col*72 + quad*8];
    bfrag8 a1 = *(bfrag8*)&src[col*72 + 32 + quad*8];
    const short* Bt = h ? Wuvst : Wusvt;
    const float* M  = h ? nv16 : av16;
    float uva[3][4] = {};
    for (int n=0;n<32;n++){
        f32x4 acc = {0.f,0.f,0.f,0.f};
        const short* bp = Bt + (size_t)((n<<5) + o0 + col)*64 + quad*8;
        bfrag8 b0 = *(const bfrag8*)(bp);
        bfrag8 b1 = *(const bfrag8*)(bp + 32);
        acc = MFMA(a0,b0,acc);
        acc = MFMA(a1,b1,acc);
        #pragma unroll
        for (int reg=0;reg<4;reg++){
            int nd = quad*4+reg;
            float m0 = M[nd*100 + n*3];
            float m1 = M[nd*100 + n*3+1];
            float m2 = M[nd*100 + n*3+2];
            uva[0][reg] += acc[reg]*m0;
            uva[1][reg] += acc[reg]*m1;
            uva[2][reg] += acc[reg]*m2;
        }
    }
    #pragma unroll
    for (int reg=0;reg<4;reg++){
        int nd = quad*4+reg;
        #pragma unroll
        for (int xx=0;xx<3;xx++)
            uvb[h][nd][(o0+col)*3+xx] = uva[xx][reg];
    }
    __syncthreads();
    {
        int nd = t>>4, j = t&15;
        float part = 0.f;
        #pragma unroll
        for (int kk=j; kk<96; kk+=16) part += uvb[0][nd][kk] + uvb[1][nd][kk];
        part += __shfl_xor(part,1); part += __shfl_xor(part,2);
        part += __shfl_xor(part,4); part += __shfl_xor(part,8);
        float mean = part*(1.0f/96.0f);
        #pragma unroll
        for (int q2=0;q2<6;q2++){
            int kk = j*6 + q2;
            float uv = uvb[0][nd][kk] + uvb[1][nd][kk];
            float g = sigm(mean*guw[kk] + gub[kk]);
            nv_out[(size_t)(nb+nd)*96 + kk] = nv16[nd*100+kk] + uv*g;
        }
    }
}

// ---------------------------------------------------------------- out = ns@Wout/8
__global__ __launch_bounds__(256) void k_out(const float* __restrict__ ns,
                                             const short* __restrict__ Woutt,
                                             float* __restrict__ outp)
{
    __shared__ __align__(16) short nsbf[16*72];
    const int t = threadIdx.x;
    const int w = t>>6, lane = t&63, col = lane&15, quad = lane>>4;
    const int nb = blockIdx.x*16;
    for (int idx=t; idx<1024; idx+=256){ int nd=idx>>6, i=idx&63;
        nsbf[nd*72+i] = f2bf(ns[(size_t)(nb+nd)*64+i]); }
    __syncthreads();
    bfrag8 a0 = *(bfrag8*)&nsbf[col*72 + quad*8];
    bfrag8 a1 = *(bfrag8*)&nsbf[col*72 + 32 + quad*8];
    #pragma unroll
    for (int nt=0;nt<4;nt++){
        int o = w*64 + nt*16 + col;
        const short* bp = Woutt + (size_t)o*64 + quad*8;
        bfrag8 b0 = *(const bfrag8*)bp;
        bfrag8 b1 = *(const bfrag8*)(bp+32);
        f32x4 acc = {0.f,0.f,0.f,0.f};
        acc = MFMA(a0,b0,acc);
        acc = MFMA(a1,b1,acc);
        #pragma unroll
        for (int reg=0;reg<4;reg++)
            outp[(size_t)(nb + quad*4+reg)*256 + o] = acc[reg];
    }
}

// ---------------------------------------------------------------- launch
extern "C" void kernel_launch(void* const* d_in, const int* in_sizes, int n_in,
                              void* d_out, int out_size, void* d_ws, size_t ws_size,
                              hipStream_t stream)
{
    const float* x     = (const float*)d_in[0];
    const float* eattr = (const float*)d_in[1];
    const float* Win   = (const float*)d_in[2];
    const float* Wout  = (const float*)d_in[3];
    const float* Wss   = (const float*)d_in[4];
    const float* Wvv0  = (const float*)d_in[5];
    const float* Wsv   = (const float*)d_in[6];
    const float* Wvs   = (const float*)d_in[7];
    const float* gmw   = (const float*)d_in[8];
    const float* gmb   = (const float*)d_in[9];
    const float* Wuss  = (const float*)d_in[10];
    const float* Wuvv  = (const float*)d_in[11];
    const float* Wusv  = (const float*)d_in[12];
    const float* Wuvs  = (const float*)d_in[13];
    const float* guw   = (const float*)d_in[14];
    const float* gub   = (const float*)d_in[15];
    const int*   eidx  = (const int*)d_in[16];
    float* outp = (float*)d_out;

    char* p = (char*)d_ws;
    float* ns_a = (float*)p; p += (size_t)N_NODES*64*4;
    float* ns_b = (float*)p; p += (size_t)N_NODES*64*4;
    float* nv_a = (float*)p; p += (size_t)N_NODES*96*4;
    float* nv_b = (float*)p; p += (size_t)N_NODES*96*4;
    float* a_s  = (float*)p; p += (size_t)N_NODES*64*4;   // a_s,a_v contiguous (one memset)
    float* a_v  = (float*)p; p += (size_t)N_NODES*96*4;
    int*   cnt    = (int*)p;   p += (size_t)N_NODES*4;
    int*   cursor = (int*)p;   p += (size_t)N_NODES*4;
    int*   col_s  = (int*)p;   p += (size_t)N_EDGES*4;
    int*   row_s  = (int*)p;   p += (size_t)N_EDGES*4;
    float4* ea_s  = (float4*)p; p += (size_t)N_EDGES*16;
    short* wp   = (short*)p;

    k_prep<<<3720, 256, 0, stream>>>(Wss,Wvv0,Wsv,Wvs,Wuss,Wuvv,Wusv,Wuvs,Wout,wp);
    hipMemsetAsync(nv_a, 0, (size_t)N_NODES*96*4, stream);
    hipMemsetAsync(cnt, 0, (size_t)N_NODES*4, stream);
    k_in<<<N_NODES/4, 256, 0, stream>>>(x, Win, ns_a);
    k_hist<<<N_EDGES/256, 256, 0, stream>>>(eidx, cnt);
    k_scan<<<1, 256, 0, stream>>>(cnt, cursor);
    k_scatter<<<N_EDGES/256, 256, 0, stream>>>(eidx, eattr, cursor, col_s, row_s, ea_s);

    for (int l=0;l<2;l++){
        const float* cns = l ? ns_b : ns_a;
        const float* cnv = l ? nv_b : nv_a;
        float* nns = l ? ns_a : ns_b;
        float* nnv = l ? nv_a : nv_b;
        hipMemsetAsync(a_s, 0, (size_t)N_NODES*(64+96)*4, stream);
        k_edge<<<N_EDGES/256, 256, 0, stream>>>(cns, cnv, col_s, row_s, ea_s,
                                         wp + (size_t)l*PREP_L,
                                         gmw + l*96, gmb + l*96, a_s, a_v);
        k_uv<<<N_NODES/16, 256, 0, stream>>>(cns, cnv, a_s, a_v,
                                             wp + (size_t)l*PREP_L + 336896,
                                             wp + (size_t)l*PREP_L + 402432,
                                             guw + l*96, gub + l*96, nnv);
        k_us<<<N_NODES/16, 256, 0, stream>>>(cns, cnv, a_s, a_v,
                                             wp + (size_t)l*PREP_L + 9216, nns);
    }
    k_out<<<N_NODES/16, 256, 0, stream>>>(ns_a, wp + (size_t)2*PREP_L, outp);
}

// Round 7
// 1390.533 us; speedup vs baseline: 1.0894x; 1.0199x over previous
//
#include <hip/hip_runtime.h>

#define N_NODES 32768
#define N_EDGES 1048576
#define PREP_L  467968   // prepped bf16 weights per layer

typedef short bfrag8 __attribute__((ext_vector_type(8)));
typedef float f32x4  __attribute__((ext_vector_type(4)));

#define MFMA(a,b,c) __builtin_amdgcn_mfma_f32_16x16x32_bf16(a,b,c,0,0,0)

__device__ __forceinline__ short f2bf(float f){
    unsigned u = __float_as_uint(f);
    u += 0x7fffu + ((u >> 16) & 1u);
    return (short)(u >> 16);
}
__device__ __forceinline__ float bf2f(short s){
    return __uint_as_float(((unsigned)(unsigned short)s) << 16);
}
__device__ __forceinline__ float sigm(float x){ return 1.0f/(1.0f + __expf(-x)); }
__device__ __forceinline__ float siluf(float x){ return x * sigm(x); }

// ---------------------------------------------------------------- weight prep
__global__ void k_prep(const float* Wss, const float* Wvv0, const float* Wsv,
                       const float* Wvs, const float* Wuss, const float* Wuvv,
                       const float* Wusv, const float* Wuvs, const float* Wout,
                       short* wp)
{
    int idx = blockIdx.x*256 + threadIdx.x;
    const int total = 2*PREP_L + 16384;
    if (idx >= total) return;
    const float s_ss  = 0.0883883476483f;  // 1/(8*sqrt2)
    const float s_vv  = 0.0721687836487f;  // (1/sqrt3)/8
    const float s_sv  = 0.0883883476483f;
    const float s_vs  = 0.125f;
    const float s_uss = 0.0110485434560f;  // 1/(64*sqrt2)
    const float s_uvv = 0.0127577593310f;  // 1/(32*sqrt6)
    const float s_uvw = 0.015625f;         // 1/64
    float v;
    if (idx >= 2*PREP_L){
        int r = idx - 2*PREP_L; int o = r >> 6, i = r & 63;
        v = Wout[i*256 + o] * 0.125f;
    } else {
        int l = idx / PREP_L; int off = idx - l*PREP_L;
        if (off < 6144){ int o = off/96, k = off - o*96;
            v = (k < 64) ? Wss[l*4096 + k*64 + o]*s_ss
                         : Wvv0[l*2048 + (k-64)*64 + o]*s_vv;
        } else if (off < 8192){ int tt = off - 6144; int m = tt>>6, i = tt&63;
            v = Wsv[l*2048 + i*32 + m]*s_sv;
        } else if (off < 9216){ int tt = off - 8192; int n = tt>>5, m = tt&31;
            v = Wvs[l*1024 + m*32 + n]*s_vs;
        } else if (off < 336896){ int tt = off - 9216; int o = tt/5120, k = tt - o*5120;
            if (k < 4096) v = Wuss[l*262144 + k*64 + o]*s_uss;
            else          v = Wuvv[l*65536 + (k-4096)*64 + o]*s_uvv;
        } else if (off < 402432){ int tt = off - 336896; int nf = tt>>6, i = tt&63;
            int n = nf>>5, o = nf&31;
            v = Wusv[l*65536 + i*1024 + n*32 + o]*s_uvw;
        } else { int tt = off - 402432; int nf = tt>>6, j = tt&63;
            int m = nf>>5, o = nf&31;
            v = Wuvs[l*65536 + m*2048 + j*32 + o]*s_uvw;
        }
    }
    wp[idx] = f2bf(v);
}

// ---------------------------------------------------------------- ns = x@Win/8
__global__ void k_in(const float* __restrict__ x, const float* __restrict__ Win,
                     float* __restrict__ ns)
{
    int wv = threadIdx.x >> 6, o = threadIdx.x & 63;
    int node = blockIdx.x*4 + wv;
    const float* xr = x + (size_t)node*64;
    float acc = 0.f;
    #pragma unroll
    for (int i=0;i<64;i++) acc += xr[i]*Win[i*64+o];
    ns[(size_t)node*64+o] = 0.125f*acc;
}

// ---------------------------------------------------------------- per-layer bf16 node-state pack
// nsbf[node][64]; nvbf[x][node][32]  (x stride 1<<20)
__global__ void k_pack(const float* __restrict__ ns, const float* __restrict__ nv,
                       short* __restrict__ nsbf, short* __restrict__ nvbf)
{
    int t = threadIdx.x;
    int nb = blockIdx.x*16;
    for (int idx=t; idx<1024; idx+=256){
        int nd = idx>>6, i = idx&63;
        nsbf[(size_t)(nb+nd)*64 + i] = f2bf(ns[(size_t)(nb+nd)*64 + i]);
    }
    for (int idx=t; idx<1536; idx+=256){
        int nd = idx/96, r = idx - nd*96;
        int x = r>>5, m = r&31;
        nvbf[((size_t)x<<20) + (size_t)(nb+nd)*32 + m] = f2bf(nv[(size_t)(nb+nd)*96 + m*3 + x]);
    }
}

// ---------------------------------------------------------------- sort: histogram
__global__ void k_hist(const int* __restrict__ eidx, int* __restrict__ cnt)
{
    int e = blockIdx.x*256 + threadIdx.x;
    atomicAdd(&cnt[eidx[e]], 1);
}

// ---------------------------------------------------------------- sort: scan (1 block)
__global__ void k_scan(const int* __restrict__ cnt, int* __restrict__ cursor)
{
    __shared__ int part[256];
    int t = threadIdx.x;
    int base = t*128;
    int s = 0;
    for (int i=0;i<128;i++) s += cnt[base+i];
    part[t] = s; __syncthreads();
    for (int off=1; off<256; off<<=1){
        int v = (t>=off) ? part[t-off] : 0;
        __syncthreads();
        part[t] += v;
        __syncthreads();
    }
    int run = part[t] - s;   // exclusive prefix
    for (int i=0;i<128;i++){ cursor[base+i] = run; run += cnt[base+i]; }
}

// ---------------------------------------------------------------- sort: scatter + pre-gather
__global__ void k_scatter(const int* __restrict__ eidx, const float* __restrict__ eattr,
                          int* __restrict__ cursor, int* __restrict__ col_s,
                          int* __restrict__ row_s, float4* __restrict__ ea_s)
{
    int e = blockIdx.x*256 + threadIdx.x;
    int r = eidx[e];
    int d = atomicAdd(&cursor[r], 1);
    row_s[d] = r;
    col_s[d] = eidx[N_EDGES + e];
    ea_s[d]  = ((const float4*)eattr)[e];
}

// ---------------------------------------------------------------- edge phase (sorted slots, bf16-packed gather)
__global__ __launch_bounds__(256, 3) void k_edge(
        const short* __restrict__ nsbf, const short* __restrict__ nvbf,
        const int* __restrict__ col_s, const int* __restrict__ row_s,
        const float4* __restrict__ ea_s,
        const short* __restrict__ wp_l,
        const float* __restrict__ gmw, const float* __restrict__ gmb,
        float* __restrict__ a_s, float* __restrict__ a_v)
{
    __shared__ __align__(16) short sA1[4][16*36];    // tvv = hv.ev (K=32)
    __shared__ __align__(16) short sA2[4][16*72];    // raw hs (K=64)
    __shared__ __align__(16) short sAv[4][3*16*36];  // raw hv per x (K=32)
    __shared__ int    sRow[4][16];
    __shared__ float4 sEv4[4][16];                   // ev.xyz, es
    __shared__ float  sAcc[24*160];                  // row-window accumulator

    const int t = threadIdx.x;
    const int w = t >> 6, lane = t & 63;
    const int col = lane & 15, quad = lane >> 4;
    const int blockStart = blockIdx.x*256;
    const int rfirst = row_s[blockStart];

    for (int i=t; i<24*160; i+=256) sAcc[i] = 0.f;

    const short* W1t  = wp_l;
    const short* Wsvt = wp_l + 6144;
    const short* Wvst = wp_l + 8192;

    bfrag8 bss[2][4], bvv[4], bsv[2][2], bvs[2];
    #pragma unroll
    for (int s=0;s<2;s++)
        #pragma unroll
        for (int nt=0;nt<4;nt++)
            bss[s][nt] = *(const bfrag8*)(W1t + (nt*16+col)*96 + s*32 + quad*8);
    #pragma unroll
    for (int nt=0;nt<4;nt++)
        bvv[nt] = *(const bfrag8*)(W1t + (nt*16+col)*96 + 64 + quad*8);
    #pragma unroll
    for (int s=0;s<2;s++)
        #pragma unroll
        for (int nt=0;nt<2;nt++)
            bsv[s][nt] = *(const bfrag8*)(Wsvt + (nt*16+col)*64 + s*32 + quad*8);
    #pragma unroll
    for (int nt=0;nt<2;nt++)
        bvs[nt] = *(const bfrag8*)(Wvst + (nt*16+col)*32 + quad*8);

    float gwv[2][3], gbv[2][3];
    #pragma unroll
    for (int h=0;h<2;h++)
        #pragma unroll
        for (int xx=0;xx<3;xx++){
            int k = (h*16+col)*3+xx;
            gwv[h][xx] = gmw[k]; gbv[h][xx] = gmb[k];
        }

    auto emit = [&](int r, int f, float v){
        int rl = r - rfirst;
        if (rl < 24) atomicAdd(&sAcc[rl*160 + f], v);
        else if (f < 64) atomicAdd(&a_s[(size_t)r*64 + f], v);
        else             atomicAdd(&a_v[(size_t)r*96 + f - 64], v);
    };

    __syncthreads();

    for (int it=0; it<4; it++){
        int tileBase = blockStart + w*64 + it*16;
        { // ---- stage: lane (quad q, edge e), bf16 source, 5x16B loads ----
            int e = col, q = quad;
            int sg = tileBase + e;
            int c = col_s[sg];
            float4 ea = ea_s[sg];
            const short* hsrc = nsbf + (size_t)c*64 + q*16;
            bfrag8 h0 = *(const bfrag8*)(hsrc);
            bfrag8 h1 = *(const bfrag8*)(hsrc + 8);
            *(bfrag8*)&sA2[w][e*72 + q*16]     = h0;
            *(bfrag8*)&sA2[w][e*72 + q*16 + 8] = h1;
            bfrag8 av[3];
            #pragma unroll
            for (int xx=0;xx<3;xx++){
                av[xx] = *(const bfrag8*)(nvbf + ((size_t)xx<<20) + (size_t)c*32 + q*8);
                *(bfrag8*)&sAv[w][xx*576 + e*36 + q*8] = av[xx];
            }
            bfrag8 vt;
            #pragma unroll
            for (int mi=0;mi<8;mi++)
                vt[mi] = f2bf(bf2f(av[0][mi])*ea.x + bf2f(av[1][mi])*ea.y + bf2f(av[2][mi])*ea.z);
            *(bfrag8*)&sA1[w][e*36 + q*8] = vt;
            if (q==0){
                sRow[w][e] = row_s[sg];
                sEv4[w][e] = ea;
            }
        }
        __syncthreads();
        // ---- MFMA ----
        f32x4 accss[4], accvv[4], accp[2], accq[3][2];
        #pragma unroll
        for (int nt=0;nt<4;nt++){ accss[nt] = (f32x4){0.f,0.f,0.f,0.f};
                                  accvv[nt] = (f32x4){0.f,0.f,0.f,0.f}; }
        #pragma unroll
        for (int nt=0;nt<2;nt++) accp[nt] = (f32x4){0.f,0.f,0.f,0.f};
        #pragma unroll
        for (int xx=0;xx<3;xx++)
            #pragma unroll
            for (int nt=0;nt<2;nt++) accq[xx][nt] = (f32x4){0.f,0.f,0.f,0.f};
        {
            bfrag8 a1 = *(bfrag8*)&sA1[w][col*36 + quad*8];
            bfrag8 a20 = *(bfrag8*)&sA2[w][col*72 + quad*8];
            bfrag8 a21 = *(bfrag8*)&sA2[w][col*72 + 32 + quad*8];
            #pragma unroll
            for (int nt=0;nt<4;nt++) accss[nt] = MFMA(a20, bss[0][nt], accss[nt]);
            #pragma unroll
            for (int nt=0;nt<4;nt++) accss[nt] = MFMA(a21, bss[1][nt], accss[nt]);
            #pragma unroll
            for (int nt=0;nt<4;nt++) accvv[nt] = MFMA(a1, bvv[nt], accvv[nt]);
            #pragma unroll
            for (int nt=0;nt<2;nt++) accp[nt] = MFMA(a20, bsv[0][nt], accp[nt]);
            #pragma unroll
            for (int nt=0;nt<2;nt++) accp[nt] = MFMA(a21, bsv[1][nt], accp[nt]);
            #pragma unroll
            for (int xx=0;xx<3;xx++){
                bfrag8 avx = *(bfrag8*)&sAv[w][xx*576 + col*36 + quad*8];
                #pragma unroll
                for (int nt=0;nt<2;nt++) accq[xx][nt] = MFMA(avx, bvs[nt], accq[xx][nt]);
            }
        }

        // ---- epilogue (register-lean): pass 1 = gate means, pass 2 = emits
        float4 ev4[4];
        #pragma unroll
        for (int reg=0;reg<4;reg++) ev4[reg] = sEv4[w][quad*4+reg];
        float mean[4];
        #pragma unroll
        for (int reg=0;reg<4;reg++){
            float es = ev4[reg].w;
            float part = 0.f;
            #pragma unroll
            for (int h=0;h<2;h++){
                part += accp[h][reg]*ev4[reg].x + es*accq[0][h][reg];
                part += accp[h][reg]*ev4[reg].y + es*accq[1][h][reg];
                part += accp[h][reg]*ev4[reg].z + es*accq[2][h][reg];
            }
            part += __shfl_xor(part,1); part += __shfl_xor(part,2);
            part += __shfl_xor(part,4); part += __shfl_xor(part,8);
            mean[reg] = part*(1.0f/96.0f);
        }

        int r0 = sRow[w][0], r15 = sRow[w][15];
        bool uni = (r0 == r15);
        int rq[4];
        #pragma unroll
        for (int reg=0;reg<4;reg++) rq[reg] = sRow[w][quad*4+reg];
        bool c1 = rq[1]==rq[0], c2 = rq[2]==rq[1], c3 = rq[3]==rq[2];
        auto out4 = [&](int f, float v0, float v1, float v2, float v3){
            if (uni){
                float s = v0+v1+v2+v3;
                s += __shfl_xor(s,16); s += __shfl_xor(s,32);
                if (quad==0) emit(r0, f, s);
            } else {
                float run = v0;
                if (c1) run += v1; else { emit(rq[0], f, run); run = v1; }
                if (c2) run += v2; else { emit(rq[1], f, run); run = v2; }
                if (c3) run += v3; else { emit(rq[2], f, run); run = v3; }
                emit(rq[3], f, run);
            }
        };
        #pragma unroll
        for (int nt=0;nt<4;nt++){
            float v[4];
            #pragma unroll
            for (int reg=0;reg<4;reg++)
                v[reg] = siluf(ev4[reg].w*accss[nt][reg] + accvv[nt][reg]);
            out4(nt*16+col, v[0], v[1], v[2], v[3]);
        }
        #pragma unroll
        for (int h=0;h<2;h++)
            #pragma unroll
            for (int xx=0;xx<3;xx++){
                float v[4];
                #pragma unroll
                for (int reg=0;reg<4;reg++){
                    float evx = (xx==0) ? ev4[reg].x : ((xx==1) ? ev4[reg].y : ev4[reg].z);
                    float val = accp[h][reg]*evx + ev4[reg].w*accq[xx][h][reg];
                    v[reg] = val * sigm(mean[reg]*gwv[h][xx] + gbv[h][xx]);
                }
                out4(64 + (h*16+col)*3+xx, v[0], v[1], v[2], v[3]);
            }
        __syncthreads();
    }

    // ---- flush window to global (atomics; zeros skipped) ----
    int rlast = row_s[blockStart + 255];
    int nr = rlast - rfirst + 1; if (nr > 24) nr = 24;
    for (int i=t; i<nr*160; i+=256){
        float v = sAcc[i];
        if (v != 0.f){
            int rl = i/160, f = i - rl*160;
            int r = rfirst + rl;
            if (f < 64) atomicAdd(&a_s[(size_t)r*64 + f], v);
            else        atomicAdd(&a_v[(size_t)r*96 + f - 64], v);
        }
    }
}

// ---------------------------------------------------------------- u_s (K=5120 GEMM)
__global__ __launch_bounds__(256) void k_us(
        const float* __restrict__ ns, const float* __restrict__ nvv,
        const float* __restrict__ a_s, const float* __restrict__ a_v,
        const short* __restrict__ Wusst, float* __restrict__ ns_out)
{
    __shared__ __align__(16) float ns16[16*68];
    __shared__ __align__(16) float as16[16*68];
    __shared__ __align__(16) float nv16[16*100];
    __shared__ __align__(16) float av16[16*100];
    __shared__ __align__(16) short sA[16*1032];

    const int t = threadIdx.x;
    const int w = t>>6, lane = t&63, col = lane&15, quad = lane>>4;
    const int nb = blockIdx.x*16;

    for (int idx=t; idx<1024; idx+=256){ int nd = idx>>6, i = idx&63;
        ns16[nd*68+i] = ns[(size_t)(nb+nd)*64+i];
        as16[nd*68+i] = a_s[(size_t)(nb+nd)*64+i];
    }
    for (int idx=t; idx<1536; idx+=256){ int nd = idx/96, i = idx-nd*96;
        nv16[nd*100+i] = nvv[(size_t)(nb+nd)*96+i];
        av16[nd*100+i] = a_v[(size_t)(nb+nd)*96+i];
    }
    __syncthreads();

    f32x4 acc = {0.f,0.f,0.f,0.f};
    for (int c=0;c<5;c++){
        if (c) __syncthreads();
        if (c < 4){
            #pragma unroll
            for (int itg=0; itg<8; itg++){
                int rid = t + itg*256;
                int nd = rid & 15;
                int kk0 = (rid>>4)<<3;
                int i = (c<<4) + (kk0>>6);
                int j0 = kk0 & 63;
                float nsv = ns16[nd*68 + i];
                const float* ap = &as16[nd*68 + j0];
                float4 x0 = *(const float4*)ap;
                float4 x1 = *(const float4*)(ap+4);
                bfrag8 o8;
                o8[0]=f2bf(nsv*x0.x); o8[1]=f2bf(nsv*x0.y); o8[2]=f2bf(nsv*x0.z); o8[3]=f2bf(nsv*x0.w);
                o8[4]=f2bf(nsv*x1.x); o8[5]=f2bf(nsv*x1.y); o8[6]=f2bf(nsv*x1.z); o8[7]=f2bf(nsv*x1.w);
                *(bfrag8*)&sA[nd*1032 + kk0] = o8;
            }
        } else {
            #pragma unroll
            for (int itg=0; itg<8; itg++){
                int rid = t + itg*256;
                int nd = rid & 15;
                int kk0 = (rid>>4)<<3;
                int m = kk0>>5, n0 = kk0&31;
                float v0 = nv16[nd*100 + m*3];
                float v1 = nv16[nd*100 + m*3+1];
                float v2 = nv16[nd*100 + m*3+2];
                const float* vp = &av16[nd*100 + n0*3];
                float yf[24];
                #pragma unroll
                for (int a=0;a<6;a++){ float4 y = *(const float4*)(vp+4*a);
                    yf[4*a]=y.x; yf[4*a+1]=y.y; yf[4*a+2]=y.z; yf[4*a+3]=y.w; }
                bfrag8 o8;
                #pragma unroll
                for (int jj=0;jj<8;jj++)
                    o8[jj] = f2bf(v0*yf[jj*3] + v1*yf[jj*3+1] + v2*yf[jj*3+2]);
                *(bfrag8*)&sA[nd*1032 + kk0] = o8;
            }
        }
        __syncthreads();
        const short* bp = Wusst + (size_t)(w*16+col)*5120 + c*1024 + quad*8;
        #pragma unroll
        for (int s=0;s<32;s++){
            bfrag8 a = *(bfrag8*)&sA[col*1032 + s*32 + quad*8];
            bfrag8 b = *(const bfrag8*)(bp + s*32);
            acc = MFMA(a, b, acc);
        }
    }
    #pragma unroll
    for (int reg=0; reg<4; reg++){
        int nd = quad*4 + reg;
        int o = w*16 + col;
        ns_out[(size_t)(nb+nd)*64 + o] = ns16[nd*68 + o] + siluf(acc[reg]);
    }
}

// ---------------------------------------------------------------- u_v
__global__ __launch_bounds__(256) void k_uv(
        const float* __restrict__ ns, const float* __restrict__ nvv,
        const float* __restrict__ a_s, const float* __restrict__ a_v,
        const short* __restrict__ Wusvt, const short* __restrict__ Wuvst,
        const float* __restrict__ guw, const float* __restrict__ gub,
        float* __restrict__ nv_out)
{
    __shared__ __align__(16) short nsbf[16*72];
    __shared__ __align__(16) short asbf[16*72];
    __shared__ __align__(16) float nv16[16*100];
    __shared__ __align__(16) float av16[16*100];
    __shared__ float uvb[2][16][96];

    const int t = threadIdx.x;
    const int w = t>>6, lane = t&63, col = lane&15, quad = lane>>4;
    const int nb = blockIdx.x*16;

    for (int idx=t; idx<1024; idx+=256){ int nd = idx>>6, i = idx&63;
        nsbf[nd*72+i] = f2bf(ns[(size_t)(nb+nd)*64+i]);
        asbf[nd*72+i] = f2bf(a_s[(size_t)(nb+nd)*64+i]);
    }
    for (int idx=t; idx<1536; idx+=256){ int nd = idx/96, i = idx-nd*96;
        nv16[nd*100+i] = nvv[(size_t)(nb+nd)*96+i];
        av16[nd*100+i] = a_v[(size_t)(nb+nd)*96+i];
    }
    __syncthreads();

    const int h = w>>1, o0 = (w&1)*16;
    const short* src = h ? asbf : nsbf;
    bfrag8 a0 = *(bfrag8*)&src[col*72 + quad*8];
    bfrag8 a1 = *(bfrag8*)&src[col*72 + 32 + quad*8];
    const short* Bt = h ? Wuvst : Wusvt;
    const float* M  = h ? nv16 : av16;
    float uva[3][4] = {};
    for (int n=0;n<32;n++){
        f32x4 acc = {0.f,0.f,0.f,0.f};
        const short* bp = Bt + (size_t)((n<<5) + o0 + col)*64 + quad*8;
        bfrag8 b0 = *(const bfrag8*)(bp);
        bfrag8 b1 = *(const bfrag8*)(bp + 32);
        acc = MFMA(a0,b0,acc);
        acc = MFMA(a1,b1,acc);
        #pragma unroll
        for (int reg=0;reg<4;reg++){
            int nd = quad*4+reg;
            float m0 = M[nd*100 + n*3];
            float m1 = M[nd*100 + n*3+1];
            float m2 = M[nd*100 + n*3+2];
            uva[0][reg] += acc[reg]*m0;
            uva[1][reg] += acc[reg]*m1;
            uva[2][reg] += acc[reg]*m2;
        }
    }
    #pragma unroll
    for (int reg=0;reg<4;reg++){
        int nd = quad*4+reg;
        #pragma unroll
        for (int xx=0;xx<3;xx++)
            uvb[h][nd][(o0+col)*3+xx] = uva[xx][reg];
    }
    __syncthreads();
    {
        int nd = t>>4, j = t&15;
        float part = 0.f;
        #pragma unroll
        for (int kk=j; kk<96; kk+=16) part += uvb[0][nd][kk] + uvb[1][nd][kk];
        part += __shfl_xor(part,1); part += __shfl_xor(part,2);
        part += __shfl_xor(part,4); part += __shfl_xor(part,8);
        float mean = part*(1.0f/96.0f);
        #pragma unroll
        for (int q2=0;q2<6;q2++){
            int kk = j*6 + q2;
            float uv = uvb[0][nd][kk] + uvb[1][nd][kk];
            float g = sigm(mean*guw[kk] + gub[kk]);
            nv_out[(size_t)(nb+nd)*96 + kk] = nv16[nd*100+kk] + uv*g;
        }
    }
}

// ---------------------------------------------------------------- out = ns@Wout/8
__global__ __launch_bounds__(256) void k_out(const float* __restrict__ ns,
                                             const short* __restrict__ Woutt,
                                             float* __restrict__ outp)
{
    __shared__ __align__(16) short nsbf[16*72];
    const int t = threadIdx.x;
    const int w = t>>6, lane = t&63, col = lane&15, quad = lane>>4;
    const int nb = blockIdx.x*16;
    for (int idx=t; idx<1024; idx+=256){ int nd=idx>>6, i=idx&63;
        nsbf[nd*72+i] = f2bf(ns[(size_t)(nb+nd)*64+i]); }
    __syncthreads();
    bfrag8 a0 = *(bfrag8*)&nsbf[col*72 + quad*8];
    bfrag8 a1 = *(bfrag8*)&nsbf[col*72 + 32 + quad*8];
    #pragma unroll
    for (int nt=0;nt<4;nt++){
        int o = w*64 + nt*16 + col;
        const short* bp = Woutt + (size_t)o*64 + quad*8;
        bfrag8 b0 = *(const bfrag8*)bp;
        bfrag8 b1 = *(const bfrag8*)(bp+32);
        f32x4 acc = {0.f,0.f,0.f,0.f};
        acc = MFMA(a0,b0,acc);
        acc = MFMA(a1,b1,acc);
        #pragma unroll
        for (int reg=0;reg<4;reg++)
            outp[(size_t)(nb + quad*4+reg)*256 + o] = acc[reg];
    }
}

// ---------------------------------------------------------------- launch
extern "C" void kernel_launch(void* const* d_in, const int* in_sizes, int n_in,
                              void* d_out, int out_size, void* d_ws, size_t ws_size,
                              hipStream_t stream)
{
    const float* x     = (const float*)d_in[0];
    const float* eattr = (const float*)d_in[1];
    const float* Win   = (const float*)d_in[2];
    const float* Wout  = (const float*)d_in[3];
    const float* Wss   = (const float*)d_in[4];
    const float* Wvv0  = (const float*)d_in[5];
    const float* Wsv   = (const float*)d_in[6];
    const float* Wvs   = (const float*)d_in[7];
    const float* gmw   = (const float*)d_in[8];
    const float* gmb   = (const float*)d_in[9];
    const float* Wuss  = (const float*)d_in[10];
    const float* Wuvv  = (const float*)d_in[11];
    const float* Wusv  = (const float*)d_in[12];
    const float* Wuvs  = (const float*)d_in[13];
    const float* guw   = (const float*)d_in[14];
    const float* gub   = (const float*)d_in[15];
    const int*   eidx  = (const int*)d_in[16];
    float* outp = (float*)d_out;

    char* p = (char*)d_ws;
    float* ns_a = (float*)p; p += (size_t)N_NODES*64*4;
    float* ns_b = (float*)p; p += (size_t)N_NODES*64*4;
    float* nv_a = (float*)p; p += (size_t)N_NODES*96*4;
    float* nv_b = (float*)p; p += (size_t)N_NODES*96*4;
    float* a_s  = (float*)p; p += (size_t)N_NODES*64*4;   // a_s,a_v contiguous (one memset)
    float* a_v  = (float*)p; p += (size_t)N_NODES*96*4;
    int*   cnt    = (int*)p;   p += (size_t)N_NODES*4;
    int*   cursor = (int*)p;   p += (size_t)N_NODES*4;
    int*   col_s  = (int*)p;   p += (size_t)N_EDGES*4;
    int*   row_s  = (int*)p;   p += (size_t)N_EDGES*4;
    float4* ea_s  = (float4*)p; p += (size_t)N_EDGES*16;
    short* wp   = (short*)p;   p += (size_t)(2*PREP_L + 16384)*2;
    short* nsbf = (short*)p;   p += (size_t)N_NODES*64*2;
    short* nvbf = (short*)p;   p += (size_t)3*N_NODES*32*2;

    k_prep<<<3720, 256, 0, stream>>>(Wss,Wvv0,Wsv,Wvs,Wuss,Wuvv,Wusv,Wuvs,Wout,wp);
    hipMemsetAsync(nv_a, 0, (size_t)N_NODES*96*4, stream);
    hipMemsetAsync(cnt, 0, (size_t)N_NODES*4, stream);
    k_in<<<N_NODES/4, 256, 0, stream>>>(x, Win, ns_a);
    k_hist<<<N_EDGES/256, 256, 0, stream>>>(eidx, cnt);
    k_scan<<<1, 256, 0, stream>>>(cnt, cursor);
    k_scatter<<<N_EDGES/256, 256, 0, stream>>>(eidx, eattr, cursor, col_s, row_s, ea_s);

    for (int l=0;l<2;l++){
        const float* cns = l ? ns_b : ns_a;
        const float* cnv = l ? nv_b : nv_a;
        float* nns = l ? ns_a : ns_b;
        float* nnv = l ? nv_a : nv_b;
        k_pack<<<N_NODES/16, 256, 0, stream>>>(cns, cnv, nsbf, nvbf);
        hipMemsetAsync(a_s, 0, (size_t)N_NODES*(64+96)*4, stream);
        k_edge<<<N_EDGES/256, 256, 0, stream>>>(nsbf, nvbf, col_s, row_s, ea_s,
                                         wp + (size_t)l*PREP_L,
                                         gmw + l*96, gmb + l*96, a_s, a_v);
        k_uv<<<N_NODES/16, 256, 0, stream>>>(cns, cnv, a_s, a_v,
                                             wp + (size_t)l*PREP_L + 336896,
                                             wp + (size_t)l*PREP_L + 402432,
                                             guw + l*96, gub + l*96, nnv);
        k_us<<<N_NODES/16, 256, 0, stream>>>(cns, cnv, a_s, a_v,
                                             wp + (size_t)l*PREP_L + 9216, nns);
    }
    k_out<<<N_NODES/16, 256, 0, stream>>>(ns_a, wp + (size_t)2*PREP_L, outp);
}

// Round 8
// 1322.621 us; speedup vs baseline: 1.1453x; 1.0513x over previous
//
#include <hip/hip_runtime.h>

#define N_NODES 32768
#define N_EDGES 1048576
#define PREP_L  467968   // prepped bf16 weights per layer

typedef short bfrag8 __attribute__((ext_vector_type(8)));
typedef float f32x4  __attribute__((ext_vector_type(4)));

#define MFMA(a,b,c) __builtin_amdgcn_mfma_f32_16x16x32_bf16(a,b,c,0,0,0)

__device__ __forceinline__ short f2bf(float f){
    unsigned u = __float_as_uint(f);
    u += 0x7fffu + ((u >> 16) & 1u);
    return (short)(u >> 16);
}
__device__ __forceinline__ float bf2f(short s){
    return __uint_as_float(((unsigned)(unsigned short)s) << 16);
}
__device__ __forceinline__ float sigm(float x){ return 1.0f/(1.0f + __expf(-x)); }
__device__ __forceinline__ float siluf(float x){ return x * sigm(x); }

// ---------------------------------------------------------------- weight prep
__global__ void k_prep(const float* Wss, const float* Wvv0, const float* Wsv,
                       const float* Wvs, const float* Wuss, const float* Wuvv,
                       const float* Wusv, const float* Wuvs, const float* Wout,
                       short* wp)
{
    int idx = blockIdx.x*256 + threadIdx.x;
    const int total = 2*PREP_L + 16384;
    if (idx >= total) return;
    const float s_ss  = 0.0883883476483f;  // 1/(8*sqrt2)
    const float s_vv  = 0.0721687836487f;  // (1/sqrt3)/8
    const float s_sv  = 0.0883883476483f;
    const float s_vs  = 0.125f;
    const float s_uss = 0.0110485434560f;  // 1/(64*sqrt2)
    const float s_uvv = 0.0127577593310f;  // 1/(32*sqrt6)
    const float s_uvw = 0.015625f;         // 1/64
    float v;
    if (idx >= 2*PREP_L){
        int r = idx - 2*PREP_L; int o = r >> 6, i = r & 63;
        v = Wout[i*256 + o] * 0.125f;
    } else {
        int l = idx / PREP_L; int off = idx - l*PREP_L;
        if (off < 6144){ int o = off/96, k = off - o*96;
            v = (k < 64) ? Wss[l*4096 + k*64 + o]*s_ss
                         : Wvv0[l*2048 + (k-64)*64 + o]*s_vv;
        } else if (off < 8192){ int tt = off - 6144; int m = tt>>6, i = tt&63;
            v = Wsv[l*2048 + i*32 + m]*s_sv;
        } else if (off < 9216){ int tt = off - 8192; int n = tt>>5, m = tt&31;
            v = Wvs[l*1024 + m*32 + n]*s_vs;
        } else if (off < 336896){ int tt = off - 9216; int o = tt/5120, k = tt - o*5120;
            if (k < 4096) v = Wuss[l*262144 + k*64 + o]*s_uss;
            else          v = Wuvv[l*65536 + (k-4096)*64 + o]*s_uvv;
        } else if (off < 402432){ int tt = off - 336896; int nf = tt>>6, i = tt&63;
            int n = nf>>5, o = nf&31;
            v = Wusv[l*65536 + i*1024 + n*32 + o]*s_uvw;
        } else { int tt = off - 402432; int nf = tt>>6, j = tt&63;
            int m = nf>>5, o = nf&31;
            v = Wuvs[l*65536 + m*2048 + j*32 + o]*s_uvw;
        }
    }
    wp[idx] = f2bf(v);
}

// ---------------------------------------------------------------- ns = x@Win/8
__global__ void k_in(const float* __restrict__ x, const float* __restrict__ Win,
                     float* __restrict__ ns)
{
    int wv = threadIdx.x >> 6, o = threadIdx.x & 63;
    int node = blockIdx.x*4 + wv;
    const float* xr = x + (size_t)node*64;
    float acc = 0.f;
    #pragma unroll
    for (int i=0;i<64;i++) acc += xr[i]*Win[i*64+o];
    ns[(size_t)node*64+o] = 0.125f*acc;
}

// ---------------------------------------------------------------- per-layer bf16 node-state pack
__global__ void k_pack(const float* __restrict__ ns, const float* __restrict__ nv,
                       short* __restrict__ nsbf, short* __restrict__ nvbf)
{
    int t = threadIdx.x;
    int nb = blockIdx.x*16;
    for (int idx=t; idx<1024; idx+=256){
        int nd = idx>>6, i = idx&63;
        nsbf[(size_t)(nb+nd)*64 + i] = f2bf(ns[(size_t)(nb+nd)*64 + i]);
    }
    for (int idx=t; idx<1536; idx+=256){
        int nd = idx/96, r = idx - nd*96;
        int x = r>>5, m = r&31;
        nvbf[((size_t)x<<20) + (size_t)(nb+nd)*32 + m] = f2bf(nv[(size_t)(nb+nd)*96 + m*3 + x]);
    }
}

// ---------------------------------------------------------------- sort: histogram
__global__ void k_hist(const int* __restrict__ eidx, int* __restrict__ cnt)
{
    int e = blockIdx.x*256 + threadIdx.x;
    atomicAdd(&cnt[eidx[e]], 1);
}

// ---------------------------------------------------------------- sort: scan (1 block) + row_ptr
__global__ void k_scan(const int* __restrict__ cnt, int* __restrict__ cursor,
                       int* __restrict__ row_ptr)
{
    __shared__ int part[256];
    int t = threadIdx.x;
    int base = t*128;
    int s = 0;
    for (int i=0;i<128;i++) s += cnt[base+i];
    part[t] = s; __syncthreads();
    for (int off=1; off<256; off<<=1){
        int v = (t>=off) ? part[t-off] : 0;
        __syncthreads();
        part[t] += v;
        __syncthreads();
    }
    int run = part[t] - s;   // exclusive prefix
    for (int i=0;i<128;i++){ cursor[base+i] = run; row_ptr[base+i] = run; run += cnt[base+i]; }
    if (t == 255) row_ptr[N_NODES] = N_EDGES;
}

// ---------------------------------------------------------------- sort: scatter + pre-gather
__global__ void k_scatter(const int* __restrict__ eidx, const float* __restrict__ eattr,
                          int* __restrict__ cursor, int* __restrict__ col_s,
                          int* __restrict__ row_s, float4* __restrict__ ea_s)
{
    int e = blockIdx.x*256 + threadIdx.x;
    int r = eidx[e];
    int d = atomicAdd(&cursor[r], 1);
    row_s[d] = r;
    col_s[d] = eidx[N_EDGES + e];
    ea_s[d]  = ((const float4*)eattr)[e];
}

// ---------------------------------------------------------------- edge phase: row-blocked CSR
// Block b owns rows [8b,8b+8) and exactly their edges. All aggregation lands in
// an 8x160 LDS window -> ZERO global atomics; flush is plain stores (covers all
// features incl. zeros, so no a_s/a_v memset). Staging LDS is per-wave-private
// -> the tile loop is barrier-free; waves grab tiles tid = w, w+4, ...
__global__ __launch_bounds__(256, 3) void k_edge(
        const short* __restrict__ nsbf, const short* __restrict__ nvbf,
        const int* __restrict__ col_s, const int* __restrict__ row_s,
        const float4* __restrict__ ea_s, const int* __restrict__ row_ptr,
        const short* __restrict__ wp_l,
        const float* __restrict__ gmw, const float* __restrict__ gmb,
        float* __restrict__ a_s, float* __restrict__ a_v)
{
    __shared__ __align__(16) short sA1[4][16*36];    // tvv = hv.ev (K=32)
    __shared__ __align__(16) short sA2[4][16*72];    // raw hs (K=64)
    __shared__ __align__(16) short sAv[4][3*16*36];  // raw hv per x (K=32)
    __shared__ int    sRow[4][16];                   // row-local (0..7)
    __shared__ float4 sEv4[4][16];                   // ev.xyz, es
    __shared__ float  sAcc[8*160];                   // row-window accumulator

    const int t = threadIdx.x;
    const int w = t >> 6, lane = t & 63;
    const int col = lane & 15, quad = lane >> 4;
    const int r0 = blockIdx.x*8;
    const int e0 = row_ptr[r0], e1 = row_ptr[r0+8];

    for (int i=t; i<8*160; i+=256) sAcc[i] = 0.f;

    const short* W1t  = wp_l;
    const short* Wsvt = wp_l + 6144;
    const short* Wvst = wp_l + 8192;

    bfrag8 bss[2][4], bvv[4], bsv[2][2], bvs[2];
    #pragma unroll
    for (int s=0;s<2;s++)
        #pragma unroll
        for (int nt=0;nt<4;nt++)
            bss[s][nt] = *(const bfrag8*)(W1t + (nt*16+col)*96 + s*32 + quad*8);
    #pragma unroll
    for (int nt=0;nt<4;nt++)
        bvv[nt] = *(const bfrag8*)(W1t + (nt*16+col)*96 + 64 + quad*8);
    #pragma unroll
    for (int s=0;s<2;s++)
        #pragma unroll
        for (int nt=0;nt<2;nt++)
            bsv[s][nt] = *(const bfrag8*)(Wsvt + (nt*16+col)*64 + s*32 + quad*8);
    #pragma unroll
    for (int nt=0;nt<2;nt++)
        bvs[nt] = *(const bfrag8*)(Wvst + (nt*16+col)*32 + quad*8);

    float gwv[2][3], gbv[2][3];
    #pragma unroll
    for (int h=0;h<2;h++)
        #pragma unroll
        for (int xx=0;xx<3;xx++){
            int k = (h*16+col)*3+xx;
            gwv[h][xx] = gmw[k]; gbv[h][xx] = gmb[k];
        }

    __syncthreads();

    const int ntiles = (e1 - e0 + 15) >> 4;
    for (int tid=w; tid<ntiles; tid+=4){
        { // ---- stage (wave-private LDS; no barrier needed) ----
            int e = col, q = quad;
            int sg = e0 + tid*16 + e;
            bool valid = sg < e1;
            int sgc = valid ? sg : (e1-1);
            int c = col_s[sgc];
            float4 ea = ea_s[sgc];
            if (!valid){ ea.x=0.f; ea.y=0.f; ea.z=0.f; ea.w=0.f; }
            const short* hsrc = nsbf + (size_t)c*64 + q*16;
            bfrag8 h0 = *(const bfrag8*)(hsrc);
            bfrag8 h1 = *(const bfrag8*)(hsrc + 8);
            *(bfrag8*)&sA2[w][e*72 + q*16]     = h0;
            *(bfrag8*)&sA2[w][e*72 + q*16 + 8] = h1;
            bfrag8 av[3];
            #pragma unroll
            for (int xx=0;xx<3;xx++){
                av[xx] = *(const bfrag8*)(nvbf + ((size_t)xx<<20) + (size_t)c*32 + q*8);
                *(bfrag8*)&sAv[w][xx*576 + e*36 + q*8] = av[xx];
            }
            bfrag8 vt;
            #pragma unroll
            for (int mi=0;mi<8;mi++)
                vt[mi] = f2bf(bf2f(av[0][mi])*ea.x + bf2f(av[1][mi])*ea.y + bf2f(av[2][mi])*ea.z);
            *(bfrag8*)&sA1[w][e*36 + q*8] = vt;
            if (q==0){
                sRow[w][e] = row_s[sgc] - r0;
                sEv4[w][e] = ea;
            }
        }
        // ---- MFMA ----
        f32x4 accss[4], accvv[4], accp[2], accq[3][2];
        #pragma unroll
        for (int nt=0;nt<4;nt++){ accss[nt] = (f32x4){0.f,0.f,0.f,0.f};
                                  accvv[nt] = (f32x4){0.f,0.f,0.f,0.f}; }
        #pragma unroll
        for (int nt=0;nt<2;nt++) accp[nt] = (f32x4){0.f,0.f,0.f,0.f};
        #pragma unroll
        for (int xx=0;xx<3;xx++)
            #pragma unroll
            for (int nt=0;nt<2;nt++) accq[xx][nt] = (f32x4){0.f,0.f,0.f,0.f};
        {
            bfrag8 a1 = *(bfrag8*)&sA1[w][col*36 + quad*8];
            bfrag8 a20 = *(bfrag8*)&sA2[w][col*72 + quad*8];
            bfrag8 a21 = *(bfrag8*)&sA2[w][col*72 + 32 + quad*8];
            #pragma unroll
            for (int nt=0;nt<4;nt++) accss[nt] = MFMA(a20, bss[0][nt], accss[nt]);
            #pragma unroll
            for (int nt=0;nt<4;nt++) accss[nt] = MFMA(a21, bss[1][nt], accss[nt]);
            #pragma unroll
            for (int nt=0;nt<4;nt++) accvv[nt] = MFMA(a1, bvv[nt], accvv[nt]);
            #pragma unroll
            for (int nt=0;nt<2;nt++) accp[nt] = MFMA(a20, bsv[0][nt], accp[nt]);
            #pragma unroll
            for (int nt=0;nt<2;nt++) accp[nt] = MFMA(a21, bsv[1][nt], accp[nt]);
            #pragma unroll
            for (int xx=0;xx<3;xx++){
                bfrag8 avx = *(bfrag8*)&sAv[w][xx*576 + col*36 + quad*8];
                #pragma unroll
                for (int nt=0;nt<2;nt++) accq[xx][nt] = MFMA(avx, bvs[nt], accq[xx][nt]);
            }
        }

        // ---- epilogue: gate means, then emits (all into LDS window) ----
        float4 ev4[4];
        #pragma unroll
        for (int reg=0;reg<4;reg++) ev4[reg] = sEv4[w][quad*4+reg];
        float mean[4];
        #pragma unroll
        for (int reg=0;reg<4;reg++){
            float es = ev4[reg].w;
            float part = 0.f;
            #pragma unroll
            for (int h=0;h<2;h++){
                part += accp[h][reg]*ev4[reg].x + es*accq[0][h][reg];
                part += accp[h][reg]*ev4[reg].y + es*accq[1][h][reg];
                part += accp[h][reg]*ev4[reg].z + es*accq[2][h][reg];
            }
            part += __shfl_xor(part,1); part += __shfl_xor(part,2);
            part += __shfl_xor(part,4); part += __shfl_xor(part,8);
            mean[reg] = part*(1.0f/96.0f);
        }

        int rl0 = sRow[w][0], rl15 = sRow[w][15];
        bool uni = (rl0 == rl15);
        int rq[4];
        #pragma unroll
        for (int reg=0;reg<4;reg++) rq[reg] = sRow[w][quad*4+reg];
        bool c1 = rq[1]==rq[0], c2 = rq[2]==rq[1], c3 = rq[3]==rq[2];
        auto out4 = [&](int f, float v0, float v1, float v2, float v3){
            if (uni){
                float s = v0+v1+v2+v3;
                s += __shfl_xor(s,16); s += __shfl_xor(s,32);
                if (quad==0) atomicAdd(&sAcc[rl0*160 + f], s);
            } else {
                float run = v0;
                if (c1) run += v1; else { atomicAdd(&sAcc[rq[0]*160 + f], run); run = v1; }
                if (c2) run += v2; else { atomicAdd(&sAcc[rq[1]*160 + f], run); run = v2; }
                if (c3) run += v3; else { atomicAdd(&sAcc[rq[2]*160 + f], run); run = v3; }
                atomicAdd(&sAcc[rq[3]*160 + f], run);
            }
        };
        #pragma unroll
        for (int nt=0;nt<4;nt++){
            float v[4];
            #pragma unroll
            for (int reg=0;reg<4;reg++)
                v[reg] = siluf(ev4[reg].w*accss[nt][reg] + accvv[nt][reg]);
            out4(nt*16+col, v[0], v[1], v[2], v[3]);
        }
        #pragma unroll
        for (int h=0;h<2;h++)
            #pragma unroll
            for (int xx=0;xx<3;xx++){
                float v[4];
                #pragma unroll
                for (int reg=0;reg<4;reg++){
                    float evx = (xx==0) ? ev4[reg].x : ((xx==1) ? ev4[reg].y : ev4[reg].z);
                    float val = accp[h][reg]*evx + ev4[reg].w*accq[xx][h][reg];
                    v[reg] = val * sigm(mean[reg]*gwv[h][xx] + gbv[h][xx]);
                }
                out4(64 + (h*16+col)*3+xx, v[0], v[1], v[2], v[3]);
            }
    }

    __syncthreads();
    // ---- flush window: plain stores, full coverage (zeros included) ----
    for (int i=t; i<8*160; i+=256){
        int rl = i/160, f = i - rl*160;
        int r = r0 + rl;
        float v = sAcc[i];
        if (f < 64) a_s[(size_t)r*64 + f] = v;
        else        a_v[(size_t)r*96 + f - 64] = v;
    }
}

// ---------------------------------------------------------------- u_s (K=5120 GEMM)
__global__ __launch_bounds__(256) void k_us(
        const float* __restrict__ ns, const float* __restrict__ nvv,
        const float* __restrict__ a_s, const float* __restrict__ a_v,
        const short* __restrict__ Wusst, float* __restrict__ ns_out)
{
    __shared__ __align__(16) float ns16[16*68];
    __shared__ __align__(16) float as16[16*68];
    __shared__ __align__(16) float nv16[16*100];
    __shared__ __align__(16) float av16[16*100];
    __shared__ __align__(16) short sA[16*1032];

    const int t = threadIdx.x;
    const int w = t>>6, lane = t&63, col = lane&15, quad = lane>>4;
    const int nb = blockIdx.x*16;

    for (int idx=t; idx<1024; idx+=256){ int nd = idx>>6, i = idx&63;
        ns16[nd*68+i] = ns[(size_t)(nb+nd)*64+i];
        as16[nd*68+i] = a_s[(size_t)(nb+nd)*64+i];
    }
    for (int idx=t; idx<1536; idx+=256){ int nd = idx/96, i = idx-nd*96;
        nv16[nd*100+i] = nvv[(size_t)(nb+nd)*96+i];
        av16[nd*100+i] = a_v[(size_t)(nb+nd)*96+i];
    }
    __syncthreads();

    f32x4 acc = {0.f,0.f,0.f,0.f};
    for (int c=0;c<5;c++){
        if (c) __syncthreads();
        if (c < 4){
            #pragma unroll
            for (int itg=0; itg<8; itg++){
                int rid = t + itg*256;
                int nd = rid & 15;
                int kk0 = (rid>>4)<<3;
                int i = (c<<4) + (kk0>>6);
                int j0 = kk0 & 63;
                float nsv = ns16[nd*68 + i];
                const float* ap = &as16[nd*68 + j0];
                float4 x0 = *(const float4*)ap;
                float4 x1 = *(const float4*)(ap+4);
                bfrag8 o8;
                o8[0]=f2bf(nsv*x0.x); o8[1]=f2bf(nsv*x0.y); o8[2]=f2bf(nsv*x0.z); o8[3]=f2bf(nsv*x0.w);
                o8[4]=f2bf(nsv*x1.x); o8[5]=f2bf(nsv*x1.y); o8[6]=f2bf(nsv*x1.z); o8[7]=f2bf(nsv*x1.w);
                *(bfrag8*)&sA[nd*1032 + kk0] = o8;
            }
        } else {
            #pragma unroll
            for (int itg=0; itg<8; itg++){
                int rid = t + itg*256;
                int nd = rid & 15;
                int kk0 = (rid>>4)<<3;
                int m = kk0>>5, n0 = kk0&31;
                float v0 = nv16[nd*100 + m*3];
                float v1 = nv16[nd*100 + m*3+1];
                float v2 = nv16[nd*100 + m*3+2];
                const float* vp = &av16[nd*100 + n0*3];
                float yf[24];
                #pragma unroll
                for (int a=0;a<6;a++){ float4 y = *(const float4*)(vp+4*a);
                    yf[4*a]=y.x; yf[4*a+1]=y.y; yf[4*a+2]=y.z; yf[4*a+3]=y.w; }
                bfrag8 o8;
                #pragma unroll
                for (int jj=0;jj<8;jj++)
                    o8[jj] = f2bf(v0*yf[jj*3] + v1*yf[jj*3+1] + v2*yf[jj*3+2]);
                *(bfrag8*)&sA[nd*1032 + kk0] = o8;
            }
        }
        __syncthreads();
        const short* bp = Wusst + (size_t)(w*16+col)*5120 + c*1024 + quad*8;
        #pragma unroll
        for (int s=0;s<32;s++){
            bfrag8 a = *(bfrag8*)&sA[col*1032 + s*32 + quad*8];
            bfrag8 b = *(const bfrag8*)(bp + s*32);
            acc = MFMA(a, b, acc);
        }
    }
    #pragma unroll
    for (int reg=0; reg<4; reg++){
        int nd = quad*4 + reg;
        int o = w*16 + col;
        ns_out[(size_t)(nb+nd)*64 + o] = ns16[nd*68 + o] + siluf(acc[reg]);
    }
}

// ---------------------------------------------------------------- u_v
__global__ __launch_bounds__(256) void k_uv(
        const float* __restrict__ ns, const float* __restrict__ nvv,
        const float* __restrict__ a_s, const float* __restrict__ a_v,
        const short* __restrict__ Wusvt, const short* __restrict__ Wuvst,
        const float* __restrict__ guw, const float* __restrict__ gub,
        float* __restrict__ nv_out)
{
    __shared__ __align__(16) short nsbf[16*72];
    __shared__ __align__(16) short asbf[16*72];
    __shared__ __align__(16) float nv16[16*100];
    __shared__ __align__(16) float av16[16*100];
    __shared__ float uvb[2][16][96];

    const int t = threadIdx.x;
    const int w = t>>6, lane = t&63, col = lane&15, quad = lane>>4;
    const int nb = blockIdx.x*16;

    for (int idx=t; idx<1024; idx+=256){ int nd = idx>>6, i = idx&63;
        nsbf[nd*72+i] = f2bf(ns[(size_t)(nb+nd)*64+i]);
        asbf[nd*72+i] = f2bf(a_s[(size_t)(nb+nd)*64+i]);
    }
    for (int idx=t; idx<1536; idx+=256){ int nd = idx/96, i = idx-nd*96;
        nv16[nd*100+i] = nvv[(size_t)(nb+nd)*96+i];
        av16[nd*100+i] = a_v[(size_t)(nb+nd)*96+i];
    }
    __syncthreads();

    const int h = w>>1, o0 = (w&1)*16;
    const short* src = h ? asbf : nsbf;
    bfrag8 a0 = *(bfrag8*)&src[col*72 + quad*8];
    bfrag8 a1 = *(bfrag8*)&src[col*72 + 32 + quad*8];
    const short* Bt = h ? Wuvst : Wusvt;
    const float* M  = h ? nv16 : av16;
    float uva[3][4] = {};
    for (int n=0;n<32;n++){
        f32x4 acc = {0.f,0.f,0.f,0.f};
        const short* bp = Bt + (size_t)((n<<5) + o0 + col)*64 + quad*8;
        bfrag8 b0 = *(const bfrag8*)(bp);
        bfrag8 b1 = *(const bfrag8*)(bp + 32);
        acc = MFMA(a0,b0,acc);
        acc = MFMA(a1,b1,acc);
        #pragma unroll
        for (int reg=0;reg<4;reg++){
            int nd = quad*4+reg;
            float m0 = M[nd*100 + n*3];
            float m1 = M[nd*100 + n*3+1];
            float m2 = M[nd*100 + n*3+2];
            uva[0][reg] += acc[reg]*m0;
            uva[1][reg] += acc[reg]*m1;
            uva[2][reg] += acc[reg]*m2;
        }
    }
    #pragma unroll
    for (int reg=0;reg<4;reg++){
        int nd = quad*4+reg;
        #pragma unroll
        for (int xx=0;xx<3;xx++)
            uvb[h][nd][(o0+col)*3+xx] = uva[xx][reg];
    }
    __syncthreads();
    {
        int nd = t>>4, j = t&15;
        float part = 0.f;
        #pragma unroll
        for (int kk=j; kk<96; kk+=16) part += uvb[0][nd][kk] + uvb[1][nd][kk];
        part += __shfl_xor(part,1); part += __shfl_xor(part,2);
        part += __shfl_xor(part,4); part += __shfl_xor(part,8);
        float mean = part*(1.0f/96.0f);
        #pragma unroll
        for (int q2=0;q2<6;q2++){
            int kk = j*6 + q2;
            float uv = uvb[0][nd][kk] + uvb[1][nd][kk];
            float g = sigm(mean*guw[kk] + gub[kk]);
            nv_out[(size_t)(nb+nd)*96 + kk] = nv16[nd*100+kk] + uv*g;
        }
    }
}

// ---------------------------------------------------------------- out = ns@Wout/8
__global__ __launch_bounds__(256) void k_out(const float* __restrict__ ns,
                                             const short* __restrict__ Woutt,
                                             float* __restrict__ outp)
{
    __shared__ __align__(16) short nsbf[16*72];
    const int t = threadIdx.x;
    const int w = t>>6, lane = t&63, col = lane&15, quad = lane>>4;
    const int nb = blockIdx.x*16;
    for (int idx=t; idx<1024; idx+=256){ int nd=idx>>6, i=idx&63;
        nsbf[nd*72+i] = f2bf(ns[(size_t)(nb+nd)*64+i]); }
    __syncthreads();
    bfrag8 a0 = *(bfrag8*)&nsbf[col*72 + quad*8];
    bfrag8 a1 = *(bfrag8*)&nsbf[col*72 + 32 + quad*8];
    #pragma unroll
    for (int nt=0;nt<4;nt++){
        int o = w*64 + nt*16 + col;
        const short* bp = Woutt + (size_t)o*64 + quad*8;
        bfrag8 b0 = *(const bfrag8*)bp;
        bfrag8 b1 = *(const bfrag8*)(bp+32);
        f32x4 acc = {0.f,0.f,0.f,0.f};
        acc = MFMA(a0,b0,acc);
        acc = MFMA(a1,b1,acc);
        #pragma unroll
        for (int reg=0;reg<4;reg++)
            outp[(size_t)(nb + quad*4+reg)*256 + o] = acc[reg];
    }
}

// ---------------------------------------------------------------- launch
extern "C" void kernel_launch(void* const* d_in, const int* in_sizes, int n_in,
                              void* d_out, int out_size, void* d_ws, size_t ws_size,
                              hipStream_t stream)
{
    const float* x     = (const float*)d_in[0];
    const float* eattr = (const float*)d_in[1];
    const float* Win   = (const float*)d_in[2];
    const float* Wout  = (const float*)d_in[3];
    const float* Wss   = (const float*)d_in[4];
    const float* Wvv0  = (const float*)d_in[5];
    const float* Wsv   = (const float*)d_in[6];
    const float* Wvs   = (const float*)d_in[7];
    const float* gmw   = (const float*)d_in[8];
    const float* gmb   = (const float*)d_in[9];
    const float* Wuss  = (const float*)d_in[10];
    const float* Wuvv  = (const float*)d_in[11];
    const float* Wusv  = (const float*)d_in[12];
    const float* Wuvs  = (const float*)d_in[13];
    const float* guw   = (const float*)d_in[14];
    const float* gub   = (const float*)d_in[15];
    const int*   eidx  = (const int*)d_in[16];
    float* outp = (float*)d_out;

    char* p = (char*)d_ws;
    float* ns_a = (float*)p; p += (size_t)N_NODES*64*4;
    float* ns_b = (float*)p; p += (size_t)N_NODES*64*4;
    float* nv_a = (float*)p; p += (size_t)N_NODES*96*4;
    float* nv_b = (float*)p; p += (size_t)N_NODES*96*4;
    float* a_s  = (float*)p; p += (size_t)N_NODES*64*4;
    float* a_v  = (float*)p; p += (size_t)N_NODES*96*4;
    int*   cnt     = (int*)p;   p += (size_t)N_NODES*4;
    int*   cursor  = (int*)p;   p += (size_t)N_NODES*4;
    int*   row_ptr = (int*)p;   p += (size_t)(N_NODES+1)*4;
    int*   col_s   = (int*)p;   p += (size_t)N_EDGES*4;
    int*   row_s   = (int*)p;   p += (size_t)N_EDGES*4;
    float4* ea_s   = (float4*)p; p += (size_t)N_EDGES*16;
    short* wp   = (short*)p;   p += (size_t)(2*PREP_L + 16384)*2;
    short* nsbf = (short*)p;   p += (size_t)N_NODES*64*2;
    short* nvbf = (short*)p;   p += (size_t)3*N_NODES*32*2;

    k_prep<<<3720, 256, 0, stream>>>(Wss,Wvv0,Wsv,Wvs,Wuss,Wuvv,Wusv,Wuvs,Wout,wp);
    hipMemsetAsync(nv_a, 0, (size_t)N_NODES*96*4, stream);
    hipMemsetAsync(cnt, 0, (size_t)N_NODES*4, stream);
    k_in<<<N_NODES/4, 256, 0, stream>>>(x, Win, ns_a);
    k_hist<<<N_EDGES/256, 256, 0, stream>>>(eidx, cnt);
    k_scan<<<1, 256, 0, stream>>>(cnt, cursor, row_ptr);
    k_scatter<<<N_EDGES/256, 256, 0, stream>>>(eidx, eattr, cursor, col_s, row_s, ea_s);

    for (int l=0;l<2;l++){
        const float* cns = l ? ns_b : ns_a;
        const float* cnv = l ? nv_b : nv_a;
        float* nns = l ? ns_a : ns_b;
        float* nnv = l ? nv_a : nv_b;
        k_pack<<<N_NODES/16, 256, 0, stream>>>(cns, cnv, nsbf, nvbf);
        k_edge<<<N_NODES/8, 256, 0, stream>>>(nsbf, nvbf, col_s, row_s, ea_s, row_ptr,
                                         wp + (size_t)l*PREP_L,
                                         gmw + l*96, gmb + l*96, a_s, a_v);
        k_uv<<<N_NODES/16, 256, 0, stream>>>(cns, cnv, a_s, a_v,
                                             wp + (size_t)l*PREP_L + 336896,
                                             wp + (size_t)l*PREP_L + 402432,
                                             guw + l*96, gub + l*96, nnv);
        k_us<<<N_NODES/16, 256, 0, stream>>>(cns, cnv, a_s, a_v,
                                             wp + (size_t)l*PREP_L + 9216, nns);
    }
    k_out<<<N_NODES/16, 256, 0, stream>>>(ns_a, wp + (size_t)2*PREP_L, outp);
}